// Round 7
// baseline (170.843 us; speedup 1.0000x reference)
//
#include <hip/hip_runtime.h>
#include <hip/hip_bf16.h>
#include <cstdint>

#define B_ 2
#define S_ 2048
#define D_ 1024
#define H_ 16
#define HD_ 64
#define M_ (B_*S_)   // 4096

#define LOG2E 1.4426950408889634f
#define C1_ (0.125f * LOG2E)   // 1/sqrt(64) * log2(e), folded into Q at GEMM epilogue

typedef unsigned short u16;
typedef __bf16 bf16x8 __attribute__((ext_vector_type(8)));
typedef u16 u16x8 __attribute__((ext_vector_type(8)));
typedef float f32x4 __attribute__((ext_vector_type(4)));
typedef float f32x16 __attribute__((ext_vector_type(16)));
typedef int i32x4 __attribute__((ext_vector_type(4)));

static __device__ __forceinline__ u16 f2bu(float f) {
  __bf16 b = (__bf16)f;
  return __builtin_bit_cast(unsigned short, b);
}
static __device__ __forceinline__ float bu2f(u16 u) {
  unsigned int v = ((unsigned int)u) << 16;
  return __builtin_bit_cast(float, v);
}

static __device__ __forceinline__ int cvtpk(float a, float b) {
  int r;
  asm("v_cvt_pk_bf16_f32 %0, %1, %2" : "=v"(r) : "v"(a), "v"(b));
  return r;
}
static __device__ __forceinline__ void plswap(int &x, int &y) {
  asm("v_permlane32_swap_b32 %0, %1" : "+v"(x), "+v"(y));
}

#define GLOAD16(g, l) __builtin_amdgcn_global_load_lds( \
    (__attribute__((address_space(1))) void*)(g), \
    (__attribute__((address_space(3))) void*)(l), 16, 0, 0)

// ---------------- mask prep: maskScaled = mask*log2e - 8 ----------------
__global__ __launch_bounds__(256) void mask_prep(const float* __restrict__ mask,
    float* __restrict__ ms) {
  const int i = blockIdx.x * 256 + threadIdx.x;   // 1024 float4s
  float4 mv = reinterpret_cast<const float4*>(mask)[i];
  float4 sm = {mv.x * LOG2E - 8.0f, mv.y * LOG2E - 8.0f,
               mv.z * LOG2E - 8.0f, mv.w * LOG2E - 8.0f};
  reinterpret_cast<float4*>(ms)[i] = sm;
}

// ---------------- LayerNorm: fp32 [4096][1024] -> bf16 h ----------------
__global__ __launch_bounds__(256) void ln_kernel(const float* __restrict__ x,
    const float* __restrict__ g, const float* __restrict__ be, u16* __restrict__ h) {
  const int row = blockIdx.x;
  const int t = threadIdx.x;
  float4 v = reinterpret_cast<const float4*>(x + (size_t)row * D_)[t];
  float s = v.x + v.y + v.z + v.w;
  float sq = v.x*v.x + v.y*v.y + v.z*v.z + v.w*v.w;
  #pragma unroll
  for (int off = 32; off >= 1; off >>= 1) {
    s  += __shfl_down(s, off);
    sq += __shfl_down(sq, off);
  }
  __shared__ float red[8];
  const int wave = t >> 6, lane = t & 63;
  if (lane == 0) { red[wave] = s; red[4 + wave] = sq; }
  __syncthreads();
  if (t == 0) {
    float ts = red[0]+red[1]+red[2]+red[3];
    float tq = red[4]+red[5]+red[6]+red[7];
    float mu = ts * (1.0f / D_);
    red[0] = mu;
    red[1] = rsqrtf(tq * (1.0f / D_) - mu*mu + 1e-5f);
  }
  __syncthreads();
  const float mu = red[0], rs = red[1];
  float4 gg = reinterpret_cast<const float4*>(g)[t];
  float4 bb = reinterpret_cast<const float4*>(be)[t];
  ushort4 o;
  o.x = f2bu((v.x - mu) * rs * gg.x + bb.x);
  o.y = f2bu((v.y - mu) * rs * gg.y + bb.y);
  o.z = f2bu((v.z - mu) * rs * gg.z + bb.z);
  o.w = f2bu((v.w - mu) * rs * gg.w + bb.w);
  reinterpret_cast<ushort4*>(h + (size_t)row * D_)[t] = o;
}

// ------------- Weight transpose+convert: W[k][n] fp32 -> Wt[n][k] bf16 -------------
__global__ __launch_bounds__(256) void wt_kernel(const float* __restrict__ W0,
    const float* __restrict__ W1, const float* __restrict__ W2, u16* __restrict__ wt) {
  const int z = blockIdx.z;
  const float* W = (z == 0) ? W0 : ((z == 1) ? W1 : W2);
  u16* out = wt + (size_t)z * D_ * D_;
  __shared__ float tile[32][33];
  const int n0 = blockIdx.x * 32, k0 = blockIdx.y * 32;
  const int tx = threadIdx.x, ty = threadIdx.y;
  #pragma unroll
  for (int j = 0; j < 4; ++j)
    tile[ty + 8*j][tx] = W[(size_t)(k0 + ty + 8*j) * D_ + n0 + tx];
  __syncthreads();
  #pragma unroll
  for (int j = 0; j < 4; ++j)
    out[(size_t)(n0 + ty + 8*j) * D_ + k0 + tx] = f2bu(tile[tx][ty + 8*j]);
}

// ------------- QKV GEMM: 128x128 tile, BK=32, T2-swizzled LDS -------------
// Q scaled by C1_ and stored [B,H,S,HD]; K [B,H,S,HD]; V TRANSPOSED [B,H,HD,S].
__global__ __launch_bounds__(256) void qkv_gemm(const u16* __restrict__ hbuf,
    const u16* __restrict__ wt, u16* __restrict__ qkv) {
  const int z = blockIdx.z;
  const u16* Bt = wt + (size_t)z * D_ * D_;
  u16* outp = qkv + (size_t)z * (B_*H_*S_*HD_);
  __shared__ __align__(16) u16 As[128 * 32];
  __shared__ __align__(16) u16 Bs[128 * 32];
  const int t = threadIdx.x, lane = t & 63, wave = t >> 6;
  const int row0 = blockIdx.y * 128, col0 = blockIdx.x * 128;
  const int wm = wave >> 1, wn = wave & 1;
  f32x4 acc[4][4] = {};
  const int schunk = (t & 3) ^ ((t >> 3) & 3);
  const u16* ag = hbuf + (size_t)(row0 + (t >> 2)) * D_ + schunk * 8;
  const u16* bg = Bt   + (size_t)(col0 + (t >> 2)) * D_ + schunk * 8;
  u16* lA = &As[wave * 512];
  u16* lB = &Bs[wave * 512];
  const char* Ac = (const char*)As;
  const char* Bc = (const char*)Bs;
  const int cbase = (((lane >> 4) ^ ((lane >> 1) & 3)) << 4);

  for (int k0 = 0; k0 < D_; k0 += 32) {
    GLOAD16(ag + k0,           lA);
    GLOAD16(ag + k0 + 64 * D_, lA + 2048);
    GLOAD16(bg + k0,           lB);
    GLOAD16(bg + k0 + 64 * D_, lB + 2048);
    __syncthreads();
    bf16x8 af[4], bfr[4];
    #pragma unroll
    for (int m = 0; m < 4; ++m)
      af[m] = *reinterpret_cast<const bf16x8*>(Ac + (wm*64 + m*16 + (lane & 15)) * 64 + cbase);
    #pragma unroll
    for (int n = 0; n < 4; ++n)
      bfr[n] = *reinterpret_cast<const bf16x8*>(Bc + (wn*64 + n*16 + (lane & 15)) * 64 + cbase);
    #pragma unroll
    for (int m = 0; m < 4; ++m) {
      #pragma unroll
      for (int n = 0; n < 4; ++n)
        acc[m][n] = __builtin_amdgcn_mfma_f32_16x16x32_bf16(af[m], bfr[n], acc[m][n], 0, 0, 0);
    }
    __syncthreads();
  }
  const float scl = (z == 0) ? C1_ : 1.0f;   // fold 1/sqrt(d)*log2e into Q
  #pragma unroll
  for (int m = 0; m < 4; ++m) {
    #pragma unroll
    for (int n = 0; n < 4; ++n) {
      const int gcol = col0 + wn*64 + n*16 + (lane & 15);
      const int hI = gcol >> 6, dI = gcol & 63;
      #pragma unroll
      for (int r = 0; r < 4; ++r) {
        const int grow = row0 + wm*64 + m*16 + (lane >> 4) * 4 + r;
        const int bI = grow >> 11, sI = grow & (S_ - 1);
        size_t idx;
        if (z == 2) idx = ((size_t)(bI * H_ + hI) * HD_ + dI) * S_ + sI;   // V transposed
        else        idx = ((size_t)(bI * H_ + hI) * S_ + sI) * HD_ + dI;
        outp[idx] = f2bu(acc[m][n][r] * scl);
      }
    }
  }
}

// ---- softmax + pack; defer-max, NO hot-path cross-lane ops (validated r4/r5) ----
static __device__ __forceinline__ void sm_pack(
    const f32x16& s, const float4* __restrict__ mk,
    float& dm, float& lsum, f32x16& o0, f32x16& o1,
    bf16x8& pfA, bf16x8& pfB) {
  float zb[16];
  #pragma unroll
  for (int r = 0; r < 4; ++r) {
    zb[r]      = s[r]      + ((const float*)&mk[0])[r];
    zb[r + 4]  = s[r + 4]  + ((const float*)&mk[1])[r];
    zb[r + 8]  = s[r + 8]  + ((const float*)&mk[2])[r];
    zb[r + 12] = s[r + 12] + ((const float*)&mk[3])[r];
  }
  float a0 = fmaxf(fmaxf(zb[0], zb[1]), zb[2]);
  float a1 = fmaxf(fmaxf(zb[3], zb[4]), zb[5]);
  float a2 = fmaxf(fmaxf(zb[6], zb[7]), zb[8]);
  float a3 = fmaxf(fmaxf(zb[9], zb[10]), zb[11]);
  float a4 = fmaxf(fmaxf(zb[12], zb[13]), zb[14]);
  float tm = fmaxf(fmaxf(fmaxf(a0, a1), fmaxf(a2, a3)), fmaxf(a4, zb[15]));
  if (__builtin_expect(__any(tm > dm + 8.0f), 0)) {   // cold rescale
    float tp = fmaxf(tm, __shfl_xor(tm, 32));         // full row max (q = cl)
    float dnew = fmaxf(dm, tp - 8.0f);
    float sf = __builtin_amdgcn_exp2f(dm - dnew);
    lsum *= sf; o0 = o0 * sf; o1 = o1 * sf; dm = dnew;
  }
  float p[16];
  #pragma unroll
  for (int r = 0; r < 16; ++r) p[r] = __builtin_amdgcn_exp2f(zb[r] - dm);
  float s01 = (p[0] + p[1]) + (p[2] + p[3]);
  float s23 = (p[4] + p[5]) + (p[6] + p[7]);
  float s45 = (p[8] + p[9]) + (p[10] + p[11]);
  float s67 = (p[12] + p[13]) + (p[14] + p[15]);
  lsum += (s01 + s23) + (s45 + s67);   // cross-half combine deferred to epilogue
  int pk01 = cvtpk(p[0], p[1]),   pk23 = cvtpk(p[2], p[3]);
  int pk45 = cvtpk(p[4], p[5]),   pk67 = cvtpk(p[6], p[7]);
  int pk89 = cvtpk(p[8], p[9]),   pkAB = cvtpk(p[10], p[11]);
  int pkCD = cvtpk(p[12], p[13]), pkEF = cvtpk(p[14], p[15]);
  plswap(pk01, pk45); plswap(pk23, pk67);
  plswap(pk89, pkCD); plswap(pkAB, pkEF);
  i32x4 c0 = {pk01, pk23, pk45, pk67};
  i32x4 c1 = {pk89, pkAB, pkCD, pkEF};
  pfA = __builtin_bit_cast(bf16x8, c0);
  pfB = __builtin_bit_cast(bf16x8, c1);
}

// ------------- Flash attention: kv-split across blocks, 4 waves, 4 blocks/CU -------------
// Grid 1024 = 8 XCD x (16 qtile x 2 kvhalf) x 4 plane-groups. r5-proven inner loop.
// g=0 writes unnorm fp32 O -> d_out; g=1 writes bf16 partial -> part1; merge kernel combines.
__global__ __launch_bounds__(256, 4) void attn_kernel(const u16* __restrict__ qkv,
    const float* __restrict__ maskScaled, float* __restrict__ out,
    u16* __restrict__ part1, float* __restrict__ l0a, float* __restrict__ dm0a,
    float* __restrict__ l1a, float* __restrict__ dm1a) {
  const int bid = blockIdx.x;
  const int x = bid & 7, rr = bid >> 3;
  const int w = rr & 31;                    // 16 qtiles x 2 halves per plane
  const int pidx = x + ((rr >> 5) << 3);    // plane 0..31 = b*16+h
  const int j = w & 15, g = w >> 4;
  const int hI = pidx & 15, bI = pidx >> 4;
  const size_t plane = (size_t)pidx * (S_ * HD_);
  const u16* Qp  = qkv + plane;
  const u16* Kp  = qkv + (size_t)(B_*H_*S_*HD_) + plane;
  const u16* Vtp = qkv + 2*(size_t)(B_*H_*S_*HD_) + plane;   // [d][s]
  const float* maskS = maskScaled + (size_t)bI * S_ + g * 1024;

  const int t = threadIdx.x, lane = t & 63, wave = t >> 6;
  const int cl = lane & 31, hf = lane >> 5;
  const int x7 = cl & 7;
  const int hx16 = (hf ^ x7) << 4;                 // read-side chunk XOR (bytes)
  const int rg = (cl >> 3) * 1056 + x7 * 128;      // group-padded row base (row cl)

  __shared__ __align__(16) u16 KsBuf[2][4224];     // 8 groups x 1056B per buffer
  __shared__ __align__(16) u16 VsBuf[2][4224];

  const int q0 = j * 128 + wave * 32;
  bf16x8 qf[4];   // Q pre-scaled by C1_ at GEMM epilogue
  #pragma unroll
  for (int d = 0; d < 4; ++d)
    qf[d] = *reinterpret_cast<const bf16x8*>(
        Qp + (size_t)(q0 + cl) * HD_ + d * 16 + hf * 8);

  // staging: pre-swizzled source (slot s of row r holds global chunk s^(r&7)), linear dest
  const int sr = t >> 3;                                     // row 0..31 within half
  const int scol = ((t & 7) ^ (sr & 7)) << 3;                // element col
  const u16* kSrc = Kp  + (size_t)(g * 1024 + sr) * HD_ + scol;
  const u16* vSrc = Vtp + (size_t)sr * S_ + g * 1024 + scol;
  const int dst0 = wave * 528, dst1 = (4 + wave) * 528;      // u16 offsets (1056B groups)

  f32x16 oacc0 = {}, oacc1 = {};
  float dm = 0.f, lsum = 0.f;

  GLOAD16(kSrc,                   &KsBuf[0][dst0]);
  GLOAD16(kSrc + 32 * HD_,        &KsBuf[0][dst1]);
  GLOAD16(vSrc,                   &VsBuf[0][dst0]);
  GLOAD16(vSrc + 32 * (size_t)S_, &VsBuf[0][dst1]);
  int cur = 0;

  for (int kv0 = 0; kv0 < 1024; kv0 += 64) {
    __syncthreads();   // buf[cur] ready (drains vmcnt)
    if (kv0 + 64 < 1024) {
      const u16* kn = kSrc + (size_t)(kv0 + 64) * HD_;
      const u16* vn = vSrc + (kv0 + 64);
      GLOAD16(kn,                   &KsBuf[cur ^ 1][dst0]);
      GLOAD16(kn + 32 * HD_,        &KsBuf[cur ^ 1][dst1]);
      GLOAD16(vn,                   &VsBuf[cur ^ 1][dst0]);
      GLOAD16(vn + 32 * (size_t)S_, &VsBuf[cur ^ 1][dst1]);
    }
    const char* Ks = (const char*)KsBuf[cur];
    const char* Vs = (const char*)VsBuf[cur];

    // ---- K fragments (8 x ds_read_b128) ----
    bf16x8 k0[4], k1[4];
    #pragma unroll
    for (int d = 0; d < 4; ++d) {
      k0[d] = *reinterpret_cast<const bf16x8*>(Ks + rg + ((d << 5) ^ hx16));
      k1[d] = *reinterpret_cast<const bf16x8*>(Ks + rg + 4224 + ((d << 5) ^ hx16));
    }
    // mask values (global, L1-resident, pre-scaled), hoisted
    float4 mk0[4], mk1[4];
    #pragma unroll
    for (int i = 0; i < 4; ++i) {
      mk0[i] = *reinterpret_cast<const float4*>(&maskS[kv0 + 8*i + 4*hf]);
      mk1[i] = *reinterpret_cast<const float4*>(&maskS[kv0 + 32 + 8*i + 4*hf]);
    }
    // ---- QK^T both subs (8 MFMA) ----
    f32x16 s0 = {}, s1 = {};
    __builtin_amdgcn_s_setprio(1);
    #pragma unroll
    for (int d = 0; d < 4; ++d)
      s0 = __builtin_amdgcn_mfma_f32_32x32x16_bf16(k0[d], qf[d], s0, 0, 0, 0);
    #pragma unroll
    for (int d = 0; d < 4; ++d)
      s1 = __builtin_amdgcn_mfma_f32_32x32x16_bf16(k1[d], qf[d], s1, 0, 0, 0);
    __builtin_amdgcn_s_setprio(0);

    // ---- V fragments sub0 (hoisted: LDS latency hides under softmax VALU) ----
    bf16x8 v0[4], v1[4];
    v0[0] = *reinterpret_cast<const bf16x8*>(Vs + rg + (0 ^ hx16));
    v0[1] = *reinterpret_cast<const bf16x8*>(Vs + rg + 4224 + (0 ^ hx16));
    v0[2] = *reinterpret_cast<const bf16x8*>(Vs + rg + (32 ^ hx16));
    v0[3] = *reinterpret_cast<const bf16x8*>(Vs + rg + 4224 + (32 ^ hx16));
    bf16x8 pA, pB;
    sm_pack(s0, mk0, dm, lsum, oacc0, oacc1, pA, pB);
    __builtin_amdgcn_s_setprio(1);
    oacc0 = __builtin_amdgcn_mfma_f32_32x32x16_bf16(v0[0], pA, oacc0, 0, 0, 0);
    oacc1 = __builtin_amdgcn_mfma_f32_32x32x16_bf16(v0[1], pA, oacc1, 0, 0, 0);
    oacc0 = __builtin_amdgcn_mfma_f32_32x32x16_bf16(v0[2], pB, oacc0, 0, 0, 0);
    oacc1 = __builtin_amdgcn_mfma_f32_32x32x16_bf16(v0[3], pB, oacc1, 0, 0, 0);
    __builtin_amdgcn_s_setprio(0);
    // ---- V fragments sub1 + SM1 + PV1 ----
    v1[0] = *reinterpret_cast<const bf16x8*>(Vs + rg + (64 ^ hx16));
    v1[1] = *reinterpret_cast<const bf16x8*>(Vs + rg + 4224 + (64 ^ hx16));
    v1[2] = *reinterpret_cast<const bf16x8*>(Vs + rg + (96 ^ hx16));
    v1[3] = *reinterpret_cast<const bf16x8*>(Vs + rg + 4224 + (96 ^ hx16));
    sm_pack(s1, mk1, dm, lsum, oacc0, oacc1, pA, pB);
    __builtin_amdgcn_s_setprio(1);
    oacc0 = __builtin_amdgcn_mfma_f32_32x32x16_bf16(v1[0], pA, oacc0, 0, 0, 0);
    oacc1 = __builtin_amdgcn_mfma_f32_32x32x16_bf16(v1[1], pA, oacc1, 0, 0, 0);
    oacc0 = __builtin_amdgcn_mfma_f32_32x32x16_bf16(v1[2], pB, oacc0, 0, 0, 0);
    oacc1 = __builtin_amdgcn_mfma_f32_32x32x16_bf16(v1[3], pB, oacc1, 0, 0, 0);
    __builtin_amdgcn_s_setprio(0);
    cur ^= 1;
  }

  // ---- epilogue: write UNNORMALIZED partials ----
  lsum += __shfl_xor(lsum, 32);        // full row sum for this half
  const int row = pidx * S_ + q0 + cl;
  if (g == 0) {
    float* orow = out + ((size_t)bI * S_ + q0 + cl) * D_ + hI * HD_;
    #pragma unroll
    for (int jj = 0; jj < 4; ++jj) {
      float4 o0 = {oacc0[4*jj], oacc0[4*jj+1], oacc0[4*jj+2], oacc0[4*jj+3]};
      float4 o1 = {oacc1[4*jj], oacc1[4*jj+1], oacc1[4*jj+2], oacc1[4*jj+3]};
      *reinterpret_cast<float4*>(orow + 8*jj + 4*hf)      = o0;
      *reinterpret_cast<float4*>(orow + 32 + 8*jj + 4*hf) = o1;
    }
    if (hf == 0) { l0a[row] = lsum; dm0a[row] = dm; }
  } else {
    u16* prow = part1 + (size_t)row * HD_;
    #pragma unroll
    for (int jj = 0; jj < 4; ++jj) {
      ushort4 u0 = {f2bu(oacc0[4*jj]), f2bu(oacc0[4*jj+1]), f2bu(oacc0[4*jj+2]), f2bu(oacc0[4*jj+3])};
      ushort4 u1 = {f2bu(oacc1[4*jj]), f2bu(oacc1[4*jj+1]), f2bu(oacc1[4*jj+2]), f2bu(oacc1[4*jj+3])};
      *reinterpret_cast<ushort4*>(prow + 8*jj + 4*hf)      = u0;
      *reinterpret_cast<ushort4*>(prow + 32 + 8*jj + 4*hf) = u1;
    }
    if (hf == 0) { l1a[row] = lsum; dm1a[row] = dm; }
  }
}

// ------------- merge: out = (o0*f0 + o1*f1) / (l0*f0 + l1*f1) -------------
__global__ __launch_bounds__(256) void merge_kernel(float* __restrict__ out,
    const u16* __restrict__ part1, const float* __restrict__ l0a,
    const float* __restrict__ dm0a, const float* __restrict__ l1a,
    const float* __restrict__ dm1a) {
  const int e = blockIdx.x * 256 + threadIdx.x;   // 1,048,576 threads
  const int row = e >> 4;                          // pidx*2048 + q
  const int d4 = (e & 15) << 2;
  const int pidx = row >> 11, q = row & (S_ - 1);
  const int bI = pidx >> 4, hI = pidx & 15;
  const float dm0 = dm0a[row], dm1 = dm1a[row];
  const float dd = fmaxf(dm0, dm1);
  const float f0 = __builtin_amdgcn_exp2f(dm0 - dd);
  const float f1 = __builtin_amdgcn_exp2f(dm1 - dd);
  const float rinv = 1.0f / (l0a[row] * f0 + l1a[row] * f1);
  float* op = out + ((size_t)bI * S_ + q) * D_ + hI * HD_ + d4;
  float4 o0 = *reinterpret_cast<const float4*>(op);
  ushort4 u1 = *reinterpret_cast<const ushort4*>(part1 + (size_t)row * HD_ + d4);
  float4 r;
  r.x = (o0.x * f0 + bu2f(u1.x) * f1) * rinv;
  r.y = (o0.y * f0 + bu2f(u1.y) * f1) * rinv;
  r.z = (o0.z * f0 + bu2f(u1.z) * f1) * rinv;
  r.w = (o0.w * f0 + bu2f(u1.w) * f1) * rinv;
  *reinterpret_cast<float4*>(op) = r;
}

extern "C" void kernel_launch(void* const* d_in, const int* in_sizes, int n_in,
                              void* d_out, int out_size, void* d_ws, size_t ws_size,
                              hipStream_t stream) {
  const float* x     = (const float*)d_in[0];
  const float* mask  = (const float*)d_in[1];
  const float* gamma = (const float*)d_in[2];
  const float* beta  = (const float*)d_in[3];
  const float* Wq    = (const float*)d_in[4];
  const float* Wk    = (const float*)d_in[5];
  const float* Wv    = (const float*)d_in[6];
  float* out = (float*)d_out;

  char* ws = (char*)d_ws;
  u16* hbuf = (u16*)ws;                                        // 8 MiB; reused as part1
  char* wtb = ws + (size_t)M_*D_*2;                            // 6 MiB; reused for l/dm
  u16* wt   = (u16*)wtb;
  u16* qkv  = (u16*)(ws + (size_t)M_*D_*2 + 3ull*D_*D_*2);     // 24 MiB
  float* maskScaled = (float*)(ws + (size_t)M_*D_*2 + 3ull*D_*D_*2 + 3ull*B_*H_*S_*HD_*2); // 16 KiB

  u16* part1 = hbuf;                  // 8.39 MiB (dead after gemm)
  float* l0a  = (float*)wtb;          // 4 x 256 KiB in dead wt region
  float* dm0a = (float*)(wtb + (1u<<18));
  float* l1a  = (float*)(wtb + (2u<<18));
  float* dm1a = (float*)(wtb + (3u<<18));

  hipLaunchKernelGGL(mask_prep, dim3(4), dim3(256), 0, stream, mask, maskScaled);
  hipLaunchKernelGGL(ln_kernel, dim3(M_), dim3(256), 0, stream, x, gamma, beta, hbuf);
  hipLaunchKernelGGL(wt_kernel, dim3(32, 32, 3), dim3(32, 8), 0, stream, Wq, Wk, Wv, wt);
  hipLaunchKernelGGL(qkv_gemm, dim3(8, 32, 3), dim3(256), 0, stream, hbuf, wt, qkv);
  hipLaunchKernelGGL(attn_kernel, dim3(1024), dim3(256), 0, stream, qkv, maskScaled,
                     out, part1, l0a, dm0a, l1a, dm1a);
  hipLaunchKernelGGL(merge_kernel, dim3(4096), dim3(256), 0, stream, out, part1,
                     l0a, dm0a, l1a, dm1a);
}

// Round 8
// 124.066 us; speedup vs baseline: 1.3770x; 1.3770x over previous
//
#include <hip/hip_runtime.h>
#include <hip/hip_bf16.h>
#include <cstdint>

#define B_ 2
#define S_ 2048
#define D_ 1024
#define H_ 16
#define HD_ 64
#define M_ (B_*S_)   // 4096

#define LOG2E 1.4426950408889634f
#define C1_ (0.125f * LOG2E)   // 1/sqrt(64) * log2(e), folded into Q at GEMM epilogue

typedef unsigned short u16;
typedef __bf16 bf16x8 __attribute__((ext_vector_type(8)));
typedef u16 u16x8 __attribute__((ext_vector_type(8)));
typedef float f32x4 __attribute__((ext_vector_type(4)));
typedef float f32x16 __attribute__((ext_vector_type(16)));
typedef int i32x4 __attribute__((ext_vector_type(4)));

static __device__ __forceinline__ u16 f2bu(float f) {
  __bf16 b = (__bf16)f;
  return __builtin_bit_cast(unsigned short, b);
}
static __device__ __forceinline__ float bu2f(u16 u) {
  unsigned int v = ((unsigned int)u) << 16;
  return __builtin_bit_cast(float, v);
}

static __device__ __forceinline__ int cvtpk(float a, float b) {
  int r;
  asm("v_cvt_pk_bf16_f32 %0, %1, %2" : "=v"(r) : "v"(a), "v"(b));
  return r;
}
static __device__ __forceinline__ void plswap(int &x, int &y) {
  asm("v_permlane32_swap_b32 %0, %1" : "+v"(x), "+v"(y));
}

#define GLOAD16(g, l) __builtin_amdgcn_global_load_lds( \
    (__attribute__((address_space(1))) void*)(g), \
    (__attribute__((address_space(3))) void*)(l), 16, 0, 0)

// ---------------- mask prep: maskScaled = mask*log2e - 8 ----------------
__global__ __launch_bounds__(256) void mask_prep(const float* __restrict__ mask,
    float* __restrict__ ms) {
  const int i = blockIdx.x * 256 + threadIdx.x;   // 1024 float4s
  float4 mv = reinterpret_cast<const float4*>(mask)[i];
  float4 sm = {mv.x * LOG2E - 8.0f, mv.y * LOG2E - 8.0f,
               mv.z * LOG2E - 8.0f, mv.w * LOG2E - 8.0f};
  reinterpret_cast<float4*>(ms)[i] = sm;
}

// ---------------- LayerNorm: fp32 [4096][1024] -> bf16 h ----------------
__global__ __launch_bounds__(256) void ln_kernel(const float* __restrict__ x,
    const float* __restrict__ g, const float* __restrict__ be, u16* __restrict__ h) {
  const int row = blockIdx.x;
  const int t = threadIdx.x;
  float4 v = reinterpret_cast<const float4*>(x + (size_t)row * D_)[t];
  float s = v.x + v.y + v.z + v.w;
  float sq = v.x*v.x + v.y*v.y + v.z*v.z + v.w*v.w;
  #pragma unroll
  for (int off = 32; off >= 1; off >>= 1) {
    s  += __shfl_down(s, off);
    sq += __shfl_down(sq, off);
  }
  __shared__ float red[8];
  const int wave = t >> 6, lane = t & 63;
  if (lane == 0) { red[wave] = s; red[4 + wave] = sq; }
  __syncthreads();
  if (t == 0) {
    float ts = red[0]+red[1]+red[2]+red[3];
    float tq = red[4]+red[5]+red[6]+red[7];
    float mu = ts * (1.0f / D_);
    red[0] = mu;
    red[1] = rsqrtf(tq * (1.0f / D_) - mu*mu + 1e-5f);
  }
  __syncthreads();
  const float mu = red[0], rs = red[1];
  float4 gg = reinterpret_cast<const float4*>(g)[t];
  float4 bb = reinterpret_cast<const float4*>(be)[t];
  ushort4 o;
  o.x = f2bu((v.x - mu) * rs * gg.x + bb.x);
  o.y = f2bu((v.y - mu) * rs * gg.y + bb.y);
  o.z = f2bu((v.z - mu) * rs * gg.z + bb.z);
  o.w = f2bu((v.w - mu) * rs * gg.w + bb.w);
  reinterpret_cast<ushort4*>(h + (size_t)row * D_)[t] = o;
}

// ------------- Weight transpose+convert: W[k][n] fp32 -> Wt[n][k] bf16 -------------
__global__ __launch_bounds__(256) void wt_kernel(const float* __restrict__ W0,
    const float* __restrict__ W1, const float* __restrict__ W2, u16* __restrict__ wt) {
  const int z = blockIdx.z;
  const float* W = (z == 0) ? W0 : ((z == 1) ? W1 : W2);
  u16* out = wt + (size_t)z * D_ * D_;
  __shared__ float tile[32][33];
  const int n0 = blockIdx.x * 32, k0 = blockIdx.y * 32;
  const int tx = threadIdx.x, ty = threadIdx.y;
  #pragma unroll
  for (int j = 0; j < 4; ++j)
    tile[ty + 8*j][tx] = W[(size_t)(k0 + ty + 8*j) * D_ + n0 + tx];
  __syncthreads();
  #pragma unroll
  for (int j = 0; j < 4; ++j)
    out[(size_t)(n0 + ty + 8*j) * D_ + k0 + tx] = f2bu(tile[tx][ty + 8*j]);
}

// ------------- QKV GEMM: 128x128 tile, BK=32, T2-swizzled LDS -------------
// Q scaled by C1_ and stored [B,H,S,HD]; K [B,H,S,HD]; V TRANSPOSED [B,H,HD,S].
__global__ __launch_bounds__(256) void qkv_gemm(const u16* __restrict__ hbuf,
    const u16* __restrict__ wt, u16* __restrict__ qkv) {
  const int z = blockIdx.z;
  const u16* Bt = wt + (size_t)z * D_ * D_;
  u16* outp = qkv + (size_t)z * (B_*H_*S_*HD_);
  __shared__ __align__(16) u16 As[128 * 32];
  __shared__ __align__(16) u16 Bs[128 * 32];
  const int t = threadIdx.x, lane = t & 63, wave = t >> 6;
  const int row0 = blockIdx.y * 128, col0 = blockIdx.x * 128;
  const int wm = wave >> 1, wn = wave & 1;
  f32x4 acc[4][4] = {};
  const int schunk = (t & 3) ^ ((t >> 3) & 3);
  const u16* ag = hbuf + (size_t)(row0 + (t >> 2)) * D_ + schunk * 8;
  const u16* bg = Bt   + (size_t)(col0 + (t >> 2)) * D_ + schunk * 8;
  u16* lA = &As[wave * 512];
  u16* lB = &Bs[wave * 512];
  const char* Ac = (const char*)As;
  const char* Bc = (const char*)Bs;
  const int cbase = (((lane >> 4) ^ ((lane >> 1) & 3)) << 4);

  for (int k0 = 0; k0 < D_; k0 += 32) {
    GLOAD16(ag + k0,           lA);
    GLOAD16(ag + k0 + 64 * D_, lA + 2048);
    GLOAD16(bg + k0,           lB);
    GLOAD16(bg + k0 + 64 * D_, lB + 2048);
    __syncthreads();
    bf16x8 af[4], bfr[4];
    #pragma unroll
    for (int m = 0; m < 4; ++m)
      af[m] = *reinterpret_cast<const bf16x8*>(Ac + (wm*64 + m*16 + (lane & 15)) * 64 + cbase);
    #pragma unroll
    for (int n = 0; n < 4; ++n)
      bfr[n] = *reinterpret_cast<const bf16x8*>(Bc + (wn*64 + n*16 + (lane & 15)) * 64 + cbase);
    #pragma unroll
    for (int m = 0; m < 4; ++m) {
      #pragma unroll
      for (int n = 0; n < 4; ++n)
        acc[m][n] = __builtin_amdgcn_mfma_f32_16x16x32_bf16(af[m], bfr[n], acc[m][n], 0, 0, 0);
    }
    __syncthreads();
  }
  const float scl = (z == 0) ? C1_ : 1.0f;   // fold 1/sqrt(d)*log2e into Q
  #pragma unroll
  for (int m = 0; m < 4; ++m) {
    #pragma unroll
    for (int n = 0; n < 4; ++n) {
      const int gcol = col0 + wn*64 + n*16 + (lane & 15);
      const int hI = gcol >> 6, dI = gcol & 63;
      #pragma unroll
      for (int r = 0; r < 4; ++r) {
        const int grow = row0 + wm*64 + m*16 + (lane >> 4) * 4 + r;
        const int bI = grow >> 11, sI = grow & (S_ - 1);
        size_t idx;
        if (z == 2) idx = ((size_t)(bI * H_ + hI) * HD_ + dI) * S_ + sI;   // V transposed
        else        idx = ((size_t)(bI * H_ + hI) * S_ + sI) * HD_ + dI;
        outp[idx] = f2bu(acc[m][n][r] * scl);
      }
    }
  }
}

// ---- softmax + pack; defer-max, NO hot-path cross-lane ops (validated r4/r5) ----
static __device__ __forceinline__ void sm_pack(
    const f32x16& s, const float4* __restrict__ mk,
    float& dm, float& lsum, f32x16& o0, f32x16& o1,
    bf16x8& pfA, bf16x8& pfB) {
  float zb[16];
  #pragma unroll
  for (int r = 0; r < 4; ++r) {
    zb[r]      = s[r]      + ((const float*)&mk[0])[r];
    zb[r + 4]  = s[r + 4]  + ((const float*)&mk[1])[r];
    zb[r + 8]  = s[r + 8]  + ((const float*)&mk[2])[r];
    zb[r + 12] = s[r + 12] + ((const float*)&mk[3])[r];
  }
  float a0 = fmaxf(fmaxf(zb[0], zb[1]), zb[2]);
  float a1 = fmaxf(fmaxf(zb[3], zb[4]), zb[5]);
  float a2 = fmaxf(fmaxf(zb[6], zb[7]), zb[8]);
  float a3 = fmaxf(fmaxf(zb[9], zb[10]), zb[11]);
  float a4 = fmaxf(fmaxf(zb[12], zb[13]), zb[14]);
  float tm = fmaxf(fmaxf(fmaxf(a0, a1), fmaxf(a2, a3)), fmaxf(a4, zb[15]));
  if (__builtin_expect(__any(tm > dm + 8.0f), 0)) {   // cold rescale
    float tp = fmaxf(tm, __shfl_xor(tm, 32));         // full row max (q = cl)
    float dnew = fmaxf(dm, tp - 8.0f);
    float sf = __builtin_amdgcn_exp2f(dm - dnew);
    lsum *= sf; o0 = o0 * sf; o1 = o1 * sf; dm = dnew;
  }
  float p[16];
  #pragma unroll
  for (int r = 0; r < 16; ++r) p[r] = __builtin_amdgcn_exp2f(zb[r] - dm);
  float s01 = (p[0] + p[1]) + (p[2] + p[3]);
  float s23 = (p[4] + p[5]) + (p[6] + p[7]);
  float s45 = (p[8] + p[9]) + (p[10] + p[11]);
  float s67 = (p[12] + p[13]) + (p[14] + p[15]);
  lsum += (s01 + s23) + (s45 + s67);   // cross-half combine deferred to epilogue
  int pk01 = cvtpk(p[0], p[1]),   pk23 = cvtpk(p[2], p[3]);
  int pk45 = cvtpk(p[4], p[5]),   pk67 = cvtpk(p[6], p[7]);
  int pk89 = cvtpk(p[8], p[9]),   pkAB = cvtpk(p[10], p[11]);
  int pkCD = cvtpk(p[12], p[13]), pkEF = cvtpk(p[14], p[15]);
  plswap(pk01, pk45); plswap(pk23, pk67);
  plswap(pk89, pkCD); plswap(pkAB, pkEF);
  i32x4 c0 = {pk01, pk23, pk45, pk67};
  i32x4 c1 = {pk89, pkAB, pkCD, pkEF};
  pfA = __builtin_bit_cast(bf16x8, c0);
  pfB = __builtin_bit_cast(bf16x8, c1);
}

// ------------- Flash attention: kv-split across blocks, 4 waves, 4 blocks/CU -------------
// Grid 1024 = 8 XCD x (16 qtile x 2 kvhalf) x 4 plane-groups. r5-proven inner loop.
// NOTE: launch_bounds min-waves MUST stay 2 — arg 4 clamps the allocator to 64 VGPR
// and spills ~130MB to scratch (measured r6/r7). Occupancy comes from LDS fit (4 blk/CU).
__global__ __launch_bounds__(256, 2) void attn_kernel(const u16* __restrict__ qkv,
    const float* __restrict__ maskScaled, float* __restrict__ out,
    u16* __restrict__ part1, float* __restrict__ l0a, float* __restrict__ dm0a,
    float* __restrict__ l1a, float* __restrict__ dm1a) {
  const int bid = blockIdx.x;
  const int x = bid & 7, rr = bid >> 3;
  const int w = rr & 31;                    // 16 qtiles x 2 halves per plane
  const int pidx = x + ((rr >> 5) << 3);    // plane 0..31 = b*16+h
  const int j = w & 15, g = w >> 4;
  const int hI = pidx & 15, bI = pidx >> 4;
  const size_t plane = (size_t)pidx * (S_ * HD_);
  const u16* Qp  = qkv + plane;
  const u16* Kp  = qkv + (size_t)(B_*H_*S_*HD_) + plane;
  const u16* Vtp = qkv + 2*(size_t)(B_*H_*S_*HD_) + plane;   // [d][s]
  const float* maskS = maskScaled + (size_t)bI * S_ + g * 1024;

  const int t = threadIdx.x, lane = t & 63, wave = t >> 6;
  const int cl = lane & 31, hf = lane >> 5;
  const int x7 = cl & 7;
  const int hx16 = (hf ^ x7) << 4;                 // read-side chunk XOR (bytes)
  const int rg = (cl >> 3) * 1056 + x7 * 128;      // group-padded row base (row cl)

  __shared__ __align__(16) u16 KsBuf[2][4224];     // 8 groups x 1056B per buffer
  __shared__ __align__(16) u16 VsBuf[2][4224];

  const int q0 = j * 128 + wave * 32;
  bf16x8 qf[4];   // Q pre-scaled by C1_ at GEMM epilogue
  #pragma unroll
  for (int d = 0; d < 4; ++d)
    qf[d] = *reinterpret_cast<const bf16x8*>(
        Qp + (size_t)(q0 + cl) * HD_ + d * 16 + hf * 8);

  // staging: pre-swizzled source (slot s of row r holds global chunk s^(r&7)), linear dest
  const int sr = t >> 3;                                     // row 0..31 within half
  const int scol = ((t & 7) ^ (sr & 7)) << 3;                // element col
  const u16* kSrc = Kp  + (size_t)(g * 1024 + sr) * HD_ + scol;
  const u16* vSrc = Vtp + (size_t)sr * S_ + g * 1024 + scol;
  const int dst0 = wave * 528, dst1 = (4 + wave) * 528;      // u16 offsets (1056B groups)

  f32x16 oacc0 = {}, oacc1 = {};
  float dm = 0.f, lsum = 0.f;

  GLOAD16(kSrc,                   &KsBuf[0][dst0]);
  GLOAD16(kSrc + 32 * HD_,        &KsBuf[0][dst1]);
  GLOAD16(vSrc,                   &VsBuf[0][dst0]);
  GLOAD16(vSrc + 32 * (size_t)S_, &VsBuf[0][dst1]);
  int cur = 0;

  for (int kv0 = 0; kv0 < 1024; kv0 += 64) {
    __syncthreads();   // buf[cur] ready (drains vmcnt)
    if (kv0 + 64 < 1024) {
      const u16* kn = kSrc + (size_t)(kv0 + 64) * HD_;
      const u16* vn = vSrc + (kv0 + 64);
      GLOAD16(kn,                   &KsBuf[cur ^ 1][dst0]);
      GLOAD16(kn + 32 * HD_,        &KsBuf[cur ^ 1][dst1]);
      GLOAD16(vn,                   &VsBuf[cur ^ 1][dst0]);
      GLOAD16(vn + 32 * (size_t)S_, &VsBuf[cur ^ 1][dst1]);
    }
    const char* Ks = (const char*)KsBuf[cur];
    const char* Vs = (const char*)VsBuf[cur];

    // ---- K fragments (8 x ds_read_b128) ----
    bf16x8 k0[4], k1[4];
    #pragma unroll
    for (int d = 0; d < 4; ++d) {
      k0[d] = *reinterpret_cast<const bf16x8*>(Ks + rg + ((d << 5) ^ hx16));
      k1[d] = *reinterpret_cast<const bf16x8*>(Ks + rg + 4224 + ((d << 5) ^ hx16));
    }
    // mask values (global, L1-resident, pre-scaled), hoisted
    float4 mk0[4], mk1[4];
    #pragma unroll
    for (int i = 0; i < 4; ++i) {
      mk0[i] = *reinterpret_cast<const float4*>(&maskS[kv0 + 8*i + 4*hf]);
      mk1[i] = *reinterpret_cast<const float4*>(&maskS[kv0 + 32 + 8*i + 4*hf]);
    }
    // ---- QK^T both subs (8 MFMA) ----
    f32x16 s0 = {}, s1 = {};
    __builtin_amdgcn_s_setprio(1);
    #pragma unroll
    for (int d = 0; d < 4; ++d)
      s0 = __builtin_amdgcn_mfma_f32_32x32x16_bf16(k0[d], qf[d], s0, 0, 0, 0);
    #pragma unroll
    for (int d = 0; d < 4; ++d)
      s1 = __builtin_amdgcn_mfma_f32_32x32x16_bf16(k1[d], qf[d], s1, 0, 0, 0);
    __builtin_amdgcn_s_setprio(0);

    // ---- V fragments sub0 (hoisted: LDS latency hides under softmax VALU) ----
    bf16x8 v0[4], v1[4];
    v0[0] = *reinterpret_cast<const bf16x8*>(Vs + rg + (0 ^ hx16));
    v0[1] = *reinterpret_cast<const bf16x8*>(Vs + rg + 4224 + (0 ^ hx16));
    v0[2] = *reinterpret_cast<const bf16x8*>(Vs + rg + (32 ^ hx16));
    v0[3] = *reinterpret_cast<const bf16x8*>(Vs + rg + 4224 + (32 ^ hx16));
    bf16x8 pA, pB;
    sm_pack(s0, mk0, dm, lsum, oacc0, oacc1, pA, pB);
    __builtin_amdgcn_s_setprio(1);
    oacc0 = __builtin_amdgcn_mfma_f32_32x32x16_bf16(v0[0], pA, oacc0, 0, 0, 0);
    oacc1 = __builtin_amdgcn_mfma_f32_32x32x16_bf16(v0[1], pA, oacc1, 0, 0, 0);
    oacc0 = __builtin_amdgcn_mfma_f32_32x32x16_bf16(v0[2], pB, oacc0, 0, 0, 0);
    oacc1 = __builtin_amdgcn_mfma_f32_32x32x16_bf16(v0[3], pB, oacc1, 0, 0, 0);
    __builtin_amdgcn_s_setprio(0);
    // ---- V fragments sub1 + SM1 + PV1 ----
    v1[0] = *reinterpret_cast<const bf16x8*>(Vs + rg + (64 ^ hx16));
    v1[1] = *reinterpret_cast<const bf16x8*>(Vs + rg + 4224 + (64 ^ hx16));
    v1[2] = *reinterpret_cast<const bf16x8*>(Vs + rg + (96 ^ hx16));
    v1[3] = *reinterpret_cast<const bf16x8*>(Vs + rg + 4224 + (96 ^ hx16));
    sm_pack(s1, mk1, dm, lsum, oacc0, oacc1, pA, pB);
    __builtin_amdgcn_s_setprio(1);
    oacc0 = __builtin_amdgcn_mfma_f32_32x32x16_bf16(v1[0], pA, oacc0, 0, 0, 0);
    oacc1 = __builtin_amdgcn_mfma_f32_32x32x16_bf16(v1[1], pA, oacc1, 0, 0, 0);
    oacc0 = __builtin_amdgcn_mfma_f32_32x32x16_bf16(v1[2], pB, oacc0, 0, 0, 0);
    oacc1 = __builtin_amdgcn_mfma_f32_32x32x16_bf16(v1[3], pB, oacc1, 0, 0, 0);
    __builtin_amdgcn_s_setprio(0);
    cur ^= 1;
  }

  // ---- epilogue: write UNNORMALIZED partials ----
  lsum += __shfl_xor(lsum, 32);        // full row sum for this half
  const int row = pidx * S_ + q0 + cl;
  if (g == 0) {
    float* orow = out + ((size_t)bI * S_ + q0 + cl) * D_ + hI * HD_;
    #pragma unroll
    for (int jj = 0; jj < 4; ++jj) {
      float4 o0 = {oacc0[4*jj], oacc0[4*jj+1], oacc0[4*jj+2], oacc0[4*jj+3]};
      float4 o1 = {oacc1[4*jj], oacc1[4*jj+1], oacc1[4*jj+2], oacc1[4*jj+3]};
      *reinterpret_cast<float4*>(orow + 8*jj + 4*hf)      = o0;
      *reinterpret_cast<float4*>(orow + 32 + 8*jj + 4*hf) = o1;
    }
    if (hf == 0) { l0a[row] = lsum; dm0a[row] = dm; }
  } else {
    u16* prow = part1 + (size_t)row * HD_;
    #pragma unroll
    for (int jj = 0; jj < 4; ++jj) {
      ushort4 u0 = {f2bu(oacc0[4*jj]), f2bu(oacc0[4*jj+1]), f2bu(oacc0[4*jj+2]), f2bu(oacc0[4*jj+3])};
      ushort4 u1 = {f2bu(oacc1[4*jj]), f2bu(oacc1[4*jj+1]), f2bu(oacc1[4*jj+2]), f2bu(oacc1[4*jj+3])};
      *reinterpret_cast<ushort4*>(prow + 8*jj + 4*hf)      = u0;
      *reinterpret_cast<ushort4*>(prow + 32 + 8*jj + 4*hf) = u1;
    }
    if (hf == 0) { l1a[row] = lsum; dm1a[row] = dm; }
  }
}

// ------------- merge: out = (o0*f0 + o1*f1) / (l0*f0 + l1*f1) -------------
__global__ __launch_bounds__(256) void merge_kernel(float* __restrict__ out,
    const u16* __restrict__ part1, const float* __restrict__ l0a,
    const float* __restrict__ dm0a, const float* __restrict__ l1a,
    const float* __restrict__ dm1a) {
  const int e = blockIdx.x * 256 + threadIdx.x;   // 1,048,576 threads
  const int row = e >> 4;                          // pidx*2048 + q
  const int d4 = (e & 15) << 2;
  const int pidx = row >> 11, q = row & (S_ - 1);
  const int bI = pidx >> 4, hI = pidx & 15;
  const float dm0 = dm0a[row], dm1 = dm1a[row];
  const float dd = fmaxf(dm0, dm1);
  const float f0 = __builtin_amdgcn_exp2f(dm0 - dd);
  const float f1 = __builtin_amdgcn_exp2f(dm1 - dd);
  const float rinv = 1.0f / (l0a[row] * f0 + l1a[row] * f1);
  float* op = out + ((size_t)bI * S_ + q) * D_ + hI * HD_ + d4;
  float4 o0 = *reinterpret_cast<const float4*>(op);
  ushort4 u1 = *reinterpret_cast<const ushort4*>(part1 + (size_t)row * HD_ + d4);
  float4 r;
  r.x = (o0.x * f0 + bu2f(u1.x) * f1) * rinv;
  r.y = (o0.y * f0 + bu2f(u1.y) * f1) * rinv;
  r.z = (o0.z * f0 + bu2f(u1.z) * f1) * rinv;
  r.w = (o0.w * f0 + bu2f(u1.w) * f1) * rinv;
  *reinterpret_cast<float4*>(op) = r;
}

extern "C" void kernel_launch(void* const* d_in, const int* in_sizes, int n_in,
                              void* d_out, int out_size, void* d_ws, size_t ws_size,
                              hipStream_t stream) {
  const float* x     = (const float*)d_in[0];
  const float* mask  = (const float*)d_in[1];
  const float* gamma = (const float*)d_in[2];
  const float* beta  = (const float*)d_in[3];
  const float* Wq    = (const float*)d_in[4];
  const float* Wk    = (const float*)d_in[5];
  const float* Wv    = (const float*)d_in[6];
  float* out = (float*)d_out;

  char* ws = (char*)d_ws;
  u16* hbuf = (u16*)ws;                                        // 8 MiB; reused as part1
  char* wtb = ws + (size_t)M_*D_*2;                            // 6 MiB; reused for l/dm
  u16* wt   = (u16*)wtb;
  u16* qkv  = (u16*)(ws + (size_t)M_*D_*2 + 3ull*D_*D_*2);     // 24 MiB
  float* maskScaled = (float*)(ws + (size_t)M_*D_*2 + 3ull*D_*D_*2 + 3ull*B_*H_*S_*HD_*2); // 16 KiB

  u16* part1 = hbuf;                  // 8.39 MiB (dead after gemm)
  float* l0a  = (float*)wtb;          // 4 x 256 KiB in dead wt region
  float* dm0a = (float*)(wtb + (1u<<18));
  float* l1a  = (float*)(wtb + (2u<<18));
  float* dm1a = (float*)(wtb + (3u<<18));

  hipLaunchKernelGGL(mask_prep, dim3(4), dim3(256), 0, stream, mask, maskScaled);
  hipLaunchKernelGGL(ln_kernel, dim3(M_), dim3(256), 0, stream, x, gamma, beta, hbuf);
  hipLaunchKernelGGL(wt_kernel, dim3(32, 32, 3), dim3(32, 8), 0, stream, Wq, Wk, Wv, wt);
  hipLaunchKernelGGL(qkv_gemm, dim3(8, 32, 3), dim3(256), 0, stream, hbuf, wt, qkv);
  hipLaunchKernelGGL(attn_kernel, dim3(1024), dim3(256), 0, stream, qkv, maskScaled,
                     out, part1, l0a, dm0a, l1a, dm1a);
  hipLaunchKernelGGL(merge_kernel, dim3(4096), dim3(256), 0, stream, out, part1,
                     l0a, dm0a, l1a, dm1a);
}

// Round 9
// 119.019 us; speedup vs baseline: 1.4354x; 1.0424x over previous
//
#include <hip/hip_runtime.h>
#include <hip/hip_bf16.h>
#include <cstdint>

#define B_ 2
#define S_ 2048
#define D_ 1024
#define H_ 16
#define HD_ 64
#define M_ (B_*S_)   // 4096

#define LOG2E 1.4426950408889634f
#define C1_ (0.125f * LOG2E)   // 1/sqrt(64) * log2(e), folded into Q at GEMM epilogue

typedef unsigned short u16;
typedef __bf16 bf16x8 __attribute__((ext_vector_type(8)));
typedef u16 u16x8 __attribute__((ext_vector_type(8)));
typedef float f32x4 __attribute__((ext_vector_type(4)));
typedef float f32x16 __attribute__((ext_vector_type(16)));
typedef int i32x4 __attribute__((ext_vector_type(4)));

static __device__ __forceinline__ u16 f2bu(float f) {
  __bf16 b = (__bf16)f;
  return __builtin_bit_cast(unsigned short, b);
}
static __device__ __forceinline__ float bu2f(u16 u) {
  unsigned int v = ((unsigned int)u) << 16;
  return __builtin_bit_cast(float, v);
}

static __device__ __forceinline__ int cvtpk(float a, float b) {
  int r;
  asm("v_cvt_pk_bf16_f32 %0, %1, %2" : "=v"(r) : "v"(a), "v"(b));
  return r;
}
static __device__ __forceinline__ void plswap(int &x, int &y) {
  asm("v_permlane32_swap_b32 %0, %1" : "+v"(x), "+v"(y));
}

#define GLOAD16(g, l) __builtin_amdgcn_global_load_lds( \
    (__attribute__((address_space(1))) void*)(g), \
    (__attribute__((address_space(3))) void*)(l), 16, 0, 0)

// ---------------- mask prep: maskScaled = mask*log2e - 8 ----------------
__global__ __launch_bounds__(256) void mask_prep(const float* __restrict__ mask,
    float* __restrict__ ms) {
  const int i = blockIdx.x * 256 + threadIdx.x;   // 1024 float4s
  float4 mv = reinterpret_cast<const float4*>(mask)[i];
  float4 sm = {mv.x * LOG2E - 8.0f, mv.y * LOG2E - 8.0f,
               mv.z * LOG2E - 8.0f, mv.w * LOG2E - 8.0f};
  reinterpret_cast<float4*>(ms)[i] = sm;
}

// ---------------- LayerNorm: fp32 [4096][1024] -> bf16 h ----------------
__global__ __launch_bounds__(256) void ln_kernel(const float* __restrict__ x,
    const float* __restrict__ g, const float* __restrict__ be, u16* __restrict__ h) {
  const int row = blockIdx.x;
  const int t = threadIdx.x;
  float4 v = reinterpret_cast<const float4*>(x + (size_t)row * D_)[t];
  float s = v.x + v.y + v.z + v.w;
  float sq = v.x*v.x + v.y*v.y + v.z*v.z + v.w*v.w;
  #pragma unroll
  for (int off = 32; off >= 1; off >>= 1) {
    s  += __shfl_down(s, off);
    sq += __shfl_down(sq, off);
  }
  __shared__ float red[8];
  const int wave = t >> 6, lane = t & 63;
  if (lane == 0) { red[wave] = s; red[4 + wave] = sq; }
  __syncthreads();
  if (t == 0) {
    float ts = red[0]+red[1]+red[2]+red[3];
    float tq = red[4]+red[5]+red[6]+red[7];
    float mu = ts * (1.0f / D_);
    red[0] = mu;
    red[1] = rsqrtf(tq * (1.0f / D_) - mu*mu + 1e-5f);
  }
  __syncthreads();
  const float mu = red[0], rs = red[1];
  float4 gg = reinterpret_cast<const float4*>(g)[t];
  float4 bb = reinterpret_cast<const float4*>(be)[t];
  ushort4 o;
  o.x = f2bu((v.x - mu) * rs * gg.x + bb.x);
  o.y = f2bu((v.y - mu) * rs * gg.y + bb.y);
  o.z = f2bu((v.z - mu) * rs * gg.z + bb.z);
  o.w = f2bu((v.w - mu) * rs * gg.w + bb.w);
  reinterpret_cast<ushort4*>(h + (size_t)row * D_)[t] = o;
}

// ------------- Weight transpose+convert: W[k][n] fp32 -> Wt[n][k] bf16 -------------
__global__ __launch_bounds__(256) void wt_kernel(const float* __restrict__ W0,
    const float* __restrict__ W1, const float* __restrict__ W2, u16* __restrict__ wt) {
  const int z = blockIdx.z;
  const float* W = (z == 0) ? W0 : ((z == 1) ? W1 : W2);
  u16* out = wt + (size_t)z * D_ * D_;
  __shared__ float tile[32][33];
  const int n0 = blockIdx.x * 32, k0 = blockIdx.y * 32;
  const int tx = threadIdx.x, ty = threadIdx.y;
  #pragma unroll
  for (int j = 0; j < 4; ++j)
    tile[ty + 8*j][tx] = W[(size_t)(k0 + ty + 8*j) * D_ + n0 + tx];
  __syncthreads();
  #pragma unroll
  for (int j = 0; j < 4; ++j)
    out[(size_t)(n0 + ty + 8*j) * D_ + k0 + tx] = f2bu(tile[tx][ty + 8*j]);
}

// ------------- QKV GEMM: 128x128 tile, BK=32, T2-swizzled LDS -------------
// Q scaled by C1_ and stored [B,H,S,HD]; K [B,H,S,HD]; V TRANSPOSED [B,H,HD,S].
__global__ __launch_bounds__(256) void qkv_gemm(const u16* __restrict__ hbuf,
    const u16* __restrict__ wt, u16* __restrict__ qkv) {
  const int z = blockIdx.z;
  const u16* Bt = wt + (size_t)z * D_ * D_;
  u16* outp = qkv + (size_t)z * (B_*H_*S_*HD_);
  __shared__ __align__(16) u16 As[128 * 32];
  __shared__ __align__(16) u16 Bs[128 * 32];
  const int t = threadIdx.x, lane = t & 63, wave = t >> 6;
  const int row0 = blockIdx.y * 128, col0 = blockIdx.x * 128;
  const int wm = wave >> 1, wn = wave & 1;
  f32x4 acc[4][4] = {};
  const int schunk = (t & 3) ^ ((t >> 3) & 3);
  const u16* ag = hbuf + (size_t)(row0 + (t >> 2)) * D_ + schunk * 8;
  const u16* bg = Bt   + (size_t)(col0 + (t >> 2)) * D_ + schunk * 8;
  u16* lA = &As[wave * 512];
  u16* lB = &Bs[wave * 512];
  const char* Ac = (const char*)As;
  const char* Bc = (const char*)Bs;
  const int cbase = (((lane >> 4) ^ ((lane >> 1) & 3)) << 4);

  for (int k0 = 0; k0 < D_; k0 += 32) {
    GLOAD16(ag + k0,           lA);
    GLOAD16(ag + k0 + 64 * D_, lA + 2048);
    GLOAD16(bg + k0,           lB);
    GLOAD16(bg + k0 + 64 * D_, lB + 2048);
    __syncthreads();
    bf16x8 af[4], bfr[4];
    #pragma unroll
    for (int m = 0; m < 4; ++m)
      af[m] = *reinterpret_cast<const bf16x8*>(Ac + (wm*64 + m*16 + (lane & 15)) * 64 + cbase);
    #pragma unroll
    for (int n = 0; n < 4; ++n)
      bfr[n] = *reinterpret_cast<const bf16x8*>(Bc + (wn*64 + n*16 + (lane & 15)) * 64 + cbase);
    #pragma unroll
    for (int m = 0; m < 4; ++m) {
      #pragma unroll
      for (int n = 0; n < 4; ++n)
        acc[m][n] = __builtin_amdgcn_mfma_f32_16x16x32_bf16(af[m], bfr[n], acc[m][n], 0, 0, 0);
    }
    __syncthreads();
  }
  const float scl = (z == 0) ? C1_ : 1.0f;   // fold 1/sqrt(d)*log2e into Q
  #pragma unroll
  for (int m = 0; m < 4; ++m) {
    #pragma unroll
    for (int n = 0; n < 4; ++n) {
      const int gcol = col0 + wn*64 + n*16 + (lane & 15);
      const int hI = gcol >> 6, dI = gcol & 63;
      #pragma unroll
      for (int r = 0; r < 4; ++r) {
        const int grow = row0 + wm*64 + m*16 + (lane >> 4) * 4 + r;
        const int bI = grow >> 11, sI = grow & (S_ - 1);
        size_t idx;
        if (z == 2) idx = ((size_t)(bI * H_ + hI) * HD_ + dI) * S_ + sI;   // V transposed
        else        idx = ((size_t)(bI * H_ + hI) * S_ + sI) * HD_ + dI;
        outp[idx] = f2bu(acc[m][n][r] * scl);
      }
    }
  }
}

// ---- softmax + pack; defer-max, NO hot-path cross-lane ops (validated r4/r5) ----
static __device__ __forceinline__ void sm_pack(
    const f32x16& s, const float4* __restrict__ mk,
    float& dm, float& lsum, f32x16& o0, f32x16& o1,
    bf16x8& pfA, bf16x8& pfB) {
  float zb[16];
  #pragma unroll
  for (int r = 0; r < 4; ++r) {
    zb[r]      = s[r]      + ((const float*)&mk[0])[r];
    zb[r + 4]  = s[r + 4]  + ((const float*)&mk[1])[r];
    zb[r + 8]  = s[r + 8]  + ((const float*)&mk[2])[r];
    zb[r + 12] = s[r + 12] + ((const float*)&mk[3])[r];
  }
  float a0 = fmaxf(fmaxf(zb[0], zb[1]), zb[2]);
  float a1 = fmaxf(fmaxf(zb[3], zb[4]), zb[5]);
  float a2 = fmaxf(fmaxf(zb[6], zb[7]), zb[8]);
  float a3 = fmaxf(fmaxf(zb[9], zb[10]), zb[11]);
  float a4 = fmaxf(fmaxf(zb[12], zb[13]), zb[14]);
  float tm = fmaxf(fmaxf(fmaxf(a0, a1), fmaxf(a2, a3)), fmaxf(a4, zb[15]));
  if (__builtin_expect(__any(tm > dm + 8.0f), 0)) {   // cold rescale
    float tp = fmaxf(tm, __shfl_xor(tm, 32));         // full row max (q = cl)
    float dnew = fmaxf(dm, tp - 8.0f);
    float sf = __builtin_amdgcn_exp2f(dm - dnew);
    lsum *= sf; o0 = o0 * sf; o1 = o1 * sf; dm = dnew;
  }
  float p[16];
  #pragma unroll
  for (int r = 0; r < 16; ++r) p[r] = __builtin_amdgcn_exp2f(zb[r] - dm);
  float s01 = (p[0] + p[1]) + (p[2] + p[3]);
  float s23 = (p[4] + p[5]) + (p[6] + p[7]);
  float s45 = (p[8] + p[9]) + (p[10] + p[11]);
  float s67 = (p[12] + p[13]) + (p[14] + p[15]);
  lsum += (s01 + s23) + (s45 + s67);   // cross-half combine deferred to epilogue
  int pk01 = cvtpk(p[0], p[1]),   pk23 = cvtpk(p[2], p[3]);
  int pk45 = cvtpk(p[4], p[5]),   pk67 = cvtpk(p[6], p[7]);
  int pk89 = cvtpk(p[8], p[9]),   pkAB = cvtpk(p[10], p[11]);
  int pkCD = cvtpk(p[12], p[13]), pkEF = cvtpk(p[14], p[15]);
  plswap(pk01, pk45); plswap(pk23, pk67);
  plswap(pk89, pkCD); plswap(pkAB, pkEF);
  i32x4 c0 = {pk01, pk23, pk45, pk67};
  i32x4 c1 = {pk89, pkAB, pkCD, pkEF};
  pfA = __builtin_bit_cast(bf16x8, c0);
  pfB = __builtin_bit_cast(bf16x8, c1);
}

// ------------- Flash attention: kv-split across blocks, single-sub pipeline -------------
// Grid 1024 = 8 XCD x (16 qtile x 2 kvhalf) x 4 plane-groups.
// Single-sub (32-kv at a time) to cut live regs ~80; launch_bounds(256,3) -> 170-reg
// budget -> 3 blocks/CU (12 waves). NOTE: arg 4 (=128 regs) spills ~130MB (r6/r7);
// arg 2 (=256 regs) caps residency at 8 waves/CU (r8).
__global__ __launch_bounds__(256, 3) void attn_kernel(const u16* __restrict__ qkv,
    const float* __restrict__ maskScaled, float* __restrict__ out,
    u16* __restrict__ part1, float* __restrict__ l0a, float* __restrict__ dm0a,
    float* __restrict__ l1a, float* __restrict__ dm1a) {
  const int bid = blockIdx.x;
  const int x = bid & 7, rr = bid >> 3;
  const int w = rr & 31;                    // 16 qtiles x 2 halves per plane
  const int pidx = x + ((rr >> 5) << 3);    // plane 0..31 = b*16+h
  const int j = w & 15, g = w >> 4;
  const int hI = pidx & 15, bI = pidx >> 4;
  const size_t plane = (size_t)pidx * (S_ * HD_);
  const u16* Qp  = qkv + plane;
  const u16* Kp  = qkv + (size_t)(B_*H_*S_*HD_) + plane;
  const u16* Vtp = qkv + 2*(size_t)(B_*H_*S_*HD_) + plane;   // [d][s]
  const float* maskS = maskScaled + (size_t)bI * S_ + g * 1024;

  const int t = threadIdx.x, lane = t & 63, wave = t >> 6;
  const int cl = lane & 31, hf = lane >> 5;
  const int x7 = cl & 7;
  const int hx16 = (hf ^ x7) << 4;                 // read-side chunk XOR (bytes)
  const int rg = (cl >> 3) * 1056 + x7 * 128;      // group-padded row base (row cl)

  __shared__ __align__(16) u16 KsBuf[2][4224];     // 8 groups x 1056B per buffer
  __shared__ __align__(16) u16 VsBuf[2][4224];

  const int q0 = j * 128 + wave * 32;
  bf16x8 qf[4];   // Q pre-scaled by C1_ at GEMM epilogue
  #pragma unroll
  for (int d = 0; d < 4; ++d)
    qf[d] = *reinterpret_cast<const bf16x8*>(
        Qp + (size_t)(q0 + cl) * HD_ + d * 16 + hf * 8);

  // staging: pre-swizzled source (slot s of row r holds global chunk s^(r&7)), linear dest
  const int sr = t >> 3;                                     // row 0..31 within half
  const int scol = ((t & 7) ^ (sr & 7)) << 3;                // element col
  const u16* kSrc = Kp  + (size_t)(g * 1024 + sr) * HD_ + scol;
  const u16* vSrc = Vtp + (size_t)sr * S_ + g * 1024 + scol;
  const int dst0 = wave * 528, dst1 = (4 + wave) * 528;      // u16 offsets (1056B groups)

  f32x16 oacc0 = {}, oacc1 = {};
  float dm = 0.f, lsum = 0.f;

  GLOAD16(kSrc,                   &KsBuf[0][dst0]);
  GLOAD16(kSrc + 32 * HD_,        &KsBuf[0][dst1]);
  GLOAD16(vSrc,                   &VsBuf[0][dst0]);
  GLOAD16(vSrc + 32 * (size_t)S_, &VsBuf[0][dst1]);
  int cur = 0;

  for (int kv0 = 0; kv0 < 1024; kv0 += 64) {
    __syncthreads();   // buf[cur] ready (drains vmcnt)
    if (kv0 + 64 < 1024) {
      const u16* kn = kSrc + (size_t)(kv0 + 64) * HD_;
      const u16* vn = vSrc + (kv0 + 64);
      GLOAD16(kn,                   &KsBuf[cur ^ 1][dst0]);
      GLOAD16(kn + 32 * HD_,        &KsBuf[cur ^ 1][dst1]);
      GLOAD16(vn,                   &VsBuf[cur ^ 1][dst0]);
      GLOAD16(vn + 32 * (size_t)S_, &VsBuf[cur ^ 1][dst1]);
    }
    const char* Ks = (const char*)KsBuf[cur];
    const char* Vs = (const char*)VsBuf[cur];

    // ---- single-sub pipeline: reuse K/S/V/mask register slots across the 2 subs ----
    #pragma unroll
    for (int sub = 0; sub < 2; ++sub) {
      const int so = sub * 4224;          // K sub-block byte offset
      const int vo = sub * 64;            // V kv-chunk byte offset
      bf16x8 kf[4];
      #pragma unroll
      for (int d = 0; d < 4; ++d)
        kf[d] = *reinterpret_cast<const bf16x8*>(Ks + so + rg + ((d << 5) ^ hx16));
      f32x16 s = {};
      __builtin_amdgcn_s_setprio(1);
      #pragma unroll
      for (int d = 0; d < 4; ++d)
        s = __builtin_amdgcn_mfma_f32_32x32x16_bf16(kf[d], qf[d], s, 0, 0, 0);
      __builtin_amdgcn_s_setprio(0);
      // V fragments (hoisted: LDS latency hides under softmax VALU)
      bf16x8 vf[4];
      vf[0] = *reinterpret_cast<const bf16x8*>(Vs + rg + ((vo + 0) ^ hx16));
      vf[1] = *reinterpret_cast<const bf16x8*>(Vs + rg + 4224 + ((vo + 0) ^ hx16));
      vf[2] = *reinterpret_cast<const bf16x8*>(Vs + rg + ((vo + 32) ^ hx16));
      vf[3] = *reinterpret_cast<const bf16x8*>(Vs + rg + 4224 + ((vo + 32) ^ hx16));
      float4 mk[4];
      #pragma unroll
      for (int i = 0; i < 4; ++i)
        mk[i] = *reinterpret_cast<const float4*>(&maskS[kv0 + sub*32 + 8*i + 4*hf]);
      bf16x8 pA, pB;
      sm_pack(s, mk, dm, lsum, oacc0, oacc1, pA, pB);
      __builtin_amdgcn_s_setprio(1);
      oacc0 = __builtin_amdgcn_mfma_f32_32x32x16_bf16(vf[0], pA, oacc0, 0, 0, 0);
      oacc1 = __builtin_amdgcn_mfma_f32_32x32x16_bf16(vf[1], pA, oacc1, 0, 0, 0);
      oacc0 = __builtin_amdgcn_mfma_f32_32x32x16_bf16(vf[2], pB, oacc0, 0, 0, 0);
      oacc1 = __builtin_amdgcn_mfma_f32_32x32x16_bf16(vf[3], pB, oacc1, 0, 0, 0);
      __builtin_amdgcn_s_setprio(0);
    }
    cur ^= 1;
  }

  // ---- epilogue: write UNNORMALIZED partials ----
  lsum += __shfl_xor(lsum, 32);        // full row sum for this half
  const int row = pidx * S_ + q0 + cl;
  if (g == 0) {
    float* orow = out + ((size_t)bI * S_ + q0 + cl) * D_ + hI * HD_;
    #pragma unroll
    for (int jj = 0; jj < 4; ++jj) {
      float4 o0 = {oacc0[4*jj], oacc0[4*jj+1], oacc0[4*jj+2], oacc0[4*jj+3]};
      float4 o1 = {oacc1[4*jj], oacc1[4*jj+1], oacc1[4*jj+2], oacc1[4*jj+3]};
      *reinterpret_cast<float4*>(orow + 8*jj + 4*hf)      = o0;
      *reinterpret_cast<float4*>(orow + 32 + 8*jj + 4*hf) = o1;
    }
    if (hf == 0) { l0a[row] = lsum; dm0a[row] = dm; }
  } else {
    u16* prow = part1 + (size_t)row * HD_;
    #pragma unroll
    for (int jj = 0; jj < 4; ++jj) {
      ushort4 u0 = {f2bu(oacc0[4*jj]), f2bu(oacc0[4*jj+1]), f2bu(oacc0[4*jj+2]), f2bu(oacc0[4*jj+3])};
      ushort4 u1 = {f2bu(oacc1[4*jj]), f2bu(oacc1[4*jj+1]), f2bu(oacc1[4*jj+2]), f2bu(oacc1[4*jj+3])};
      *reinterpret_cast<ushort4*>(prow + 8*jj + 4*hf)      = u0;
      *reinterpret_cast<ushort4*>(prow + 32 + 8*jj + 4*hf) = u1;
    }
    if (hf == 0) { l1a[row] = lsum; dm1a[row] = dm; }
  }
}

// ------------- merge: out = (o0*f0 + o1*f1) / (l0*f0 + l1*f1) -------------
__global__ __launch_bounds__(256) void merge_kernel(float* __restrict__ out,
    const u16* __restrict__ part1, const float* __restrict__ l0a,
    const float* __restrict__ dm0a, const float* __restrict__ l1a,
    const float* __restrict__ dm1a) {
  const int e = blockIdx.x * 256 + threadIdx.x;   // 1,048,576 threads
  const int row = e >> 4;                          // pidx*2048 + q
  const int d4 = (e & 15) << 2;
  const int pidx = row >> 11, q = row & (S_ - 1);
  const int bI = pidx >> 4, hI = pidx & 15;
  const float dm0 = dm0a[row], dm1 = dm1a[row];
  const float dd = fmaxf(dm0, dm1);
  const float f0 = __builtin_amdgcn_exp2f(dm0 - dd);
  const float f1 = __builtin_amdgcn_exp2f(dm1 - dd);
  const float rinv = 1.0f / (l0a[row] * f0 + l1a[row] * f1);
  float* op = out + ((size_t)bI * S_ + q) * D_ + hI * HD_ + d4;
  float4 o0 = *reinterpret_cast<const float4*>(op);
  ushort4 u1 = *reinterpret_cast<const ushort4*>(part1 + (size_t)row * HD_ + d4);
  float4 r;
  r.x = (o0.x * f0 + bu2f(u1.x) * f1) * rinv;
  r.y = (o0.y * f0 + bu2f(u1.y) * f1) * rinv;
  r.z = (o0.z * f0 + bu2f(u1.z) * f1) * rinv;
  r.w = (o0.w * f0 + bu2f(u1.w) * f1) * rinv;
  *reinterpret_cast<float4*>(op) = r;
}

extern "C" void kernel_launch(void* const* d_in, const int* in_sizes, int n_in,
                              void* d_out, int out_size, void* d_ws, size_t ws_size,
                              hipStream_t stream) {
  const float* x     = (const float*)d_in[0];
  const float* mask  = (const float*)d_in[1];
  const float* gamma = (const float*)d_in[2];
  const float* beta  = (const float*)d_in[3];
  const float* Wq    = (const float*)d_in[4];
  const float* Wk    = (const float*)d_in[5];
  const float* Wv    = (const float*)d_in[6];
  float* out = (float*)d_out;

  char* ws = (char*)d_ws;
  u16* hbuf = (u16*)ws;                                        // 8 MiB; reused as part1
  char* wtb = ws + (size_t)M_*D_*2;                            // 6 MiB; reused for l/dm
  u16* wt   = (u16*)wtb;
  u16* qkv  = (u16*)(ws + (size_t)M_*D_*2 + 3ull*D_*D_*2);     // 24 MiB
  float* maskScaled = (float*)(ws + (size_t)M_*D_*2 + 3ull*D_*D_*2 + 3ull*B_*H_*S_*HD_*2); // 16 KiB

  u16* part1 = hbuf;                  // 8.39 MiB (dead after gemm)
  float* l0a  = (float*)wtb;          // 4 x 256 KiB in dead wt region
  float* dm0a = (float*)(wtb + (1u<<18));
  float* l1a  = (float*)(wtb + (2u<<18));
  float* dm1a = (float*)(wtb + (3u<<18));

  hipLaunchKernelGGL(mask_prep, dim3(4), dim3(256), 0, stream, mask, maskScaled);
  hipLaunchKernelGGL(ln_kernel, dim3(M_), dim3(256), 0, stream, x, gamma, beta, hbuf);
  hipLaunchKernelGGL(wt_kernel, dim3(32, 32, 3), dim3(32, 8), 0, stream, Wq, Wk, Wv, wt);
  hipLaunchKernelGGL(qkv_gemm, dim3(8, 32, 3), dim3(256), 0, stream, hbuf, wt, qkv);
  hipLaunchKernelGGL(attn_kernel, dim3(1024), dim3(256), 0, stream, qkv, maskScaled,
                     out, part1, l0a, dm0a, l1a, dm1a);
  hipLaunchKernelGGL(merge_kernel, dim3(4096), dim3(256), 0, stream, out, part1,
                     l0a, dm0a, l1a, dm1a);
}

// Round 10
// 112.632 us; speedup vs baseline: 1.5168x; 1.0567x over previous
//
#include <hip/hip_runtime.h>
#include <hip/hip_bf16.h>
#include <cstdint>

#define B_ 2
#define S_ 2048
#define D_ 1024
#define H_ 16
#define HD_ 64
#define M_ (B_*S_)   // 4096

#define LOG2E 1.4426950408889634f
#define C1_ (0.125f * LOG2E)   // 1/sqrt(64) * log2(e), folded into Q at GEMM epilogue

typedef unsigned short u16;
typedef __bf16 bf16x8 __attribute__((ext_vector_type(8)));
typedef u16 u16x8 __attribute__((ext_vector_type(8)));
typedef float f32x4 __attribute__((ext_vector_type(4)));
typedef float f32x16 __attribute__((ext_vector_type(16)));
typedef int i32x4 __attribute__((ext_vector_type(4)));

static __device__ __forceinline__ u16 f2bu(float f) {
  __bf16 b = (__bf16)f;
  return __builtin_bit_cast(unsigned short, b);
}
static __device__ __forceinline__ float bu2f(u16 u) {
  unsigned int v = ((unsigned int)u) << 16;
  return __builtin_bit_cast(float, v);
}

static __device__ __forceinline__ int cvtpk(float a, float b) {
  int r;
  asm("v_cvt_pk_bf16_f32 %0, %1, %2" : "=v"(r) : "v"(a), "v"(b));
  return r;
}
static __device__ __forceinline__ void plswap(int &x, int &y) {
  asm("v_permlane32_swap_b32 %0, %1" : "+v"(x), "+v"(y));
}

#define GLOAD16(g, l) __builtin_amdgcn_global_load_lds( \
    (__attribute__((address_space(1))) void*)(g), \
    (__attribute__((address_space(3))) void*)(l), 16, 0, 0)

// ---------------- mask prep: maskScaled = mask*log2e - 8 ----------------
__global__ __launch_bounds__(256) void mask_prep(const float* __restrict__ mask,
    float* __restrict__ ms) {
  const int i = blockIdx.x * 256 + threadIdx.x;   // 1024 float4s
  float4 mv = reinterpret_cast<const float4*>(mask)[i];
  float4 sm = {mv.x * LOG2E - 8.0f, mv.y * LOG2E - 8.0f,
               mv.z * LOG2E - 8.0f, mv.w * LOG2E - 8.0f};
  reinterpret_cast<float4*>(ms)[i] = sm;
}

// ---------------- LayerNorm: fp32 [4096][1024] -> bf16 h ----------------
__global__ __launch_bounds__(256) void ln_kernel(const float* __restrict__ x,
    const float* __restrict__ g, const float* __restrict__ be, u16* __restrict__ h) {
  const int row = blockIdx.x;
  const int t = threadIdx.x;
  float4 v = reinterpret_cast<const float4*>(x + (size_t)row * D_)[t];
  float s = v.x + v.y + v.z + v.w;
  float sq = v.x*v.x + v.y*v.y + v.z*v.z + v.w*v.w;
  #pragma unroll
  for (int off = 32; off >= 1; off >>= 1) {
    s  += __shfl_down(s, off);
    sq += __shfl_down(sq, off);
  }
  __shared__ float red[8];
  const int wave = t >> 6, lane = t & 63;
  if (lane == 0) { red[wave] = s; red[4 + wave] = sq; }
  __syncthreads();
  if (t == 0) {
    float ts = red[0]+red[1]+red[2]+red[3];
    float tq = red[4]+red[5]+red[6]+red[7];
    float mu = ts * (1.0f / D_);
    red[0] = mu;
    red[1] = rsqrtf(tq * (1.0f / D_) - mu*mu + 1e-5f);
  }
  __syncthreads();
  const float mu = red[0], rs = red[1];
  float4 gg = reinterpret_cast<const float4*>(g)[t];
  float4 bb = reinterpret_cast<const float4*>(be)[t];
  ushort4 o;
  o.x = f2bu((v.x - mu) * rs * gg.x + bb.x);
  o.y = f2bu((v.y - mu) * rs * gg.y + bb.y);
  o.z = f2bu((v.z - mu) * rs * gg.z + bb.z);
  o.w = f2bu((v.w - mu) * rs * gg.w + bb.w);
  reinterpret_cast<ushort4*>(h + (size_t)row * D_)[t] = o;
}

// ------------- Weight transpose+convert: W[k][n] fp32 -> Wt[n][k] bf16 -------------
__global__ __launch_bounds__(256) void wt_kernel(const float* __restrict__ W0,
    const float* __restrict__ W1, const float* __restrict__ W2, u16* __restrict__ wt) {
  const int z = blockIdx.z;
  const float* W = (z == 0) ? W0 : ((z == 1) ? W1 : W2);
  u16* out = wt + (size_t)z * D_ * D_;
  __shared__ float tile[32][33];
  const int n0 = blockIdx.x * 32, k0 = blockIdx.y * 32;
  const int tx = threadIdx.x, ty = threadIdx.y;
  #pragma unroll
  for (int j = 0; j < 4; ++j)
    tile[ty + 8*j][tx] = W[(size_t)(k0 + ty + 8*j) * D_ + n0 + tx];
  __syncthreads();
  #pragma unroll
  for (int j = 0; j < 4; ++j)
    out[(size_t)(n0 + ty + 8*j) * D_ + k0 + tx] = f2bu(tile[tx][ty + 8*j]);
}

// ------------- QKV GEMM: 128x128 tile, BK=32, T2-swizzled LDS -------------
// Q scaled by C1_ and stored [B,H,S,HD]; K [B,H,S,HD]; V TRANSPOSED [B,H,HD,S].
__global__ __launch_bounds__(256) void qkv_gemm(const u16* __restrict__ hbuf,
    const u16* __restrict__ wt, u16* __restrict__ qkv) {
  const int z = blockIdx.z;
  const u16* Bt = wt + (size_t)z * D_ * D_;
  u16* outp = qkv + (size_t)z * (B_*H_*S_*HD_);
  __shared__ __align__(16) u16 As[128 * 32];
  __shared__ __align__(16) u16 Bs[128 * 32];
  const int t = threadIdx.x, lane = t & 63, wave = t >> 6;
  const int row0 = blockIdx.y * 128, col0 = blockIdx.x * 128;
  const int wm = wave >> 1, wn = wave & 1;
  f32x4 acc[4][4] = {};
  const int schunk = (t & 3) ^ ((t >> 3) & 3);
  const u16* ag = hbuf + (size_t)(row0 + (t >> 2)) * D_ + schunk * 8;
  const u16* bg = Bt   + (size_t)(col0 + (t >> 2)) * D_ + schunk * 8;
  u16* lA = &As[wave * 512];
  u16* lB = &Bs[wave * 512];
  const char* Ac = (const char*)As;
  const char* Bc = (const char*)Bs;
  const int cbase = (((lane >> 4) ^ ((lane >> 1) & 3)) << 4);

  for (int k0 = 0; k0 < D_; k0 += 32) {
    GLOAD16(ag + k0,           lA);
    GLOAD16(ag + k0 + 64 * D_, lA + 2048);
    GLOAD16(bg + k0,           lB);
    GLOAD16(bg + k0 + 64 * D_, lB + 2048);
    __syncthreads();
    bf16x8 af[4], bfr[4];
    #pragma unroll
    for (int m = 0; m < 4; ++m)
      af[m] = *reinterpret_cast<const bf16x8*>(Ac + (wm*64 + m*16 + (lane & 15)) * 64 + cbase);
    #pragma unroll
    for (int n = 0; n < 4; ++n)
      bfr[n] = *reinterpret_cast<const bf16x8*>(Bc + (wn*64 + n*16 + (lane & 15)) * 64 + cbase);
    #pragma unroll
    for (int m = 0; m < 4; ++m) {
      #pragma unroll
      for (int n = 0; n < 4; ++n)
        acc[m][n] = __builtin_amdgcn_mfma_f32_16x16x32_bf16(af[m], bfr[n], acc[m][n], 0, 0, 0);
    }
    __syncthreads();
  }
  const float scl = (z == 0) ? C1_ : 1.0f;   // fold 1/sqrt(d)*log2e into Q
  #pragma unroll
  for (int m = 0; m < 4; ++m) {
    #pragma unroll
    for (int n = 0; n < 4; ++n) {
      const int gcol = col0 + wn*64 + n*16 + (lane & 15);
      const int hI = gcol >> 6, dI = gcol & 63;
      const int grow0 = row0 + wm*64 + m*16 + (lane >> 4) * 4;
      const int bI = grow0 >> 11, sI0 = grow0 & (S_ - 1);
      if (z == 2) {
        // V^T: lane holds 4 CONSECUTIVE s for one d -> one 8B store
        ushort4 u = {f2bu(acc[m][n][0]), f2bu(acc[m][n][1]),
                     f2bu(acc[m][n][2]), f2bu(acc[m][n][3])};
        *reinterpret_cast<ushort4*>(
            outp + ((size_t)(bI * H_ + hI) * HD_ + dI) * S_ + sI0) = u;
      } else {
        #pragma unroll
        for (int r = 0; r < 4; ++r)
          outp[((size_t)(bI * H_ + hI) * S_ + sI0 + r) * HD_ + dI] =
              f2bu(acc[m][n][r] * scl);
      }
    }
  }
}

// ---- softmax + pack; defer-max, NO hot-path cross-lane ops (validated r4/r5) ----
static __device__ __forceinline__ void sm_pack(
    const f32x16& s, const float4* __restrict__ mk,
    float& dm, float& lsum, f32x16& o0, f32x16& o1,
    bf16x8& pfA, bf16x8& pfB) {
  float zb[16];
  #pragma unroll
  for (int r = 0; r < 4; ++r) {
    zb[r]      = s[r]      + ((const float*)&mk[0])[r];
    zb[r + 4]  = s[r + 4]  + ((const float*)&mk[1])[r];
    zb[r + 8]  = s[r + 8]  + ((const float*)&mk[2])[r];
    zb[r + 12] = s[r + 12] + ((const float*)&mk[3])[r];
  }
  float a0 = fmaxf(fmaxf(zb[0], zb[1]), zb[2]);
  float a1 = fmaxf(fmaxf(zb[3], zb[4]), zb[5]);
  float a2 = fmaxf(fmaxf(zb[6], zb[7]), zb[8]);
  float a3 = fmaxf(fmaxf(zb[9], zb[10]), zb[11]);
  float a4 = fmaxf(fmaxf(zb[12], zb[13]), zb[14]);
  float tm = fmaxf(fmaxf(fmaxf(a0, a1), fmaxf(a2, a3)), fmaxf(a4, zb[15]));
  if (__builtin_expect(__any(tm > dm + 8.0f), 0)) {   // cold rescale
    float tp = fmaxf(tm, __shfl_xor(tm, 32));         // full row max (q = cl)
    float dnew = fmaxf(dm, tp - 8.0f);
    float sf = __builtin_amdgcn_exp2f(dm - dnew);
    lsum *= sf; o0 = o0 * sf; o1 = o1 * sf; dm = dnew;
  }
  float p[16];
  #pragma unroll
  for (int r = 0; r < 16; ++r) p[r] = __builtin_amdgcn_exp2f(zb[r] - dm);
  float s01 = (p[0] + p[1]) + (p[2] + p[3]);
  float s23 = (p[4] + p[5]) + (p[6] + p[7]);
  float s45 = (p[8] + p[9]) + (p[10] + p[11]);
  float s67 = (p[12] + p[13]) + (p[14] + p[15]);
  lsum += (s01 + s23) + (s45 + s67);   // cross-half combine deferred to epilogue
  int pk01 = cvtpk(p[0], p[1]),   pk23 = cvtpk(p[2], p[3]);
  int pk45 = cvtpk(p[4], p[5]),   pk67 = cvtpk(p[6], p[7]);
  int pk89 = cvtpk(p[8], p[9]),   pkAB = cvtpk(p[10], p[11]);
  int pkCD = cvtpk(p[12], p[13]), pkEF = cvtpk(p[14], p[15]);
  plswap(pk01, pk45); plswap(pk23, pk67);
  plswap(pk89, pkCD); plswap(pkAB, pkEF);
  i32x4 c0 = {pk01, pk23, pk45, pk67};
  i32x4 c1 = {pk89, pkAB, pkCD, pkEF};
  pfA = __builtin_bit_cast(bf16x8, c0);
  pfB = __builtin_bit_cast(bf16x8, c1);
}

// ------------- Flash attention: kv-split across blocks, SINGLE-buffered K/V -------------
// Grid 1024 = 8 XCD x (16 qtile x 2 kvhalf) x 4 plane-groups.
// LDS 16896B -> 4 blocks/CU resident (r9's 33.8KB fit only ~3). Staging latency per
// tile is exposed within a block but covered by 16 waves/CU TLP.
__global__ __launch_bounds__(256, 3) void attn_kernel(const u16* __restrict__ qkv,
    const float* __restrict__ maskScaled, float* __restrict__ out,
    u16* __restrict__ part1, float* __restrict__ l0a, float* __restrict__ dm0a,
    float* __restrict__ l1a, float* __restrict__ dm1a) {
  const int bid = blockIdx.x;
  const int x = bid & 7, rr = bid >> 3;
  const int w = rr & 31;                    // 16 qtiles x 2 halves per plane
  const int pidx = x + ((rr >> 5) << 3);    // plane 0..31 = b*16+h
  const int j = w & 15, g = w >> 4;
  const int hI = pidx & 15, bI = pidx >> 4;
  const size_t plane = (size_t)pidx * (S_ * HD_);
  const u16* Qp  = qkv + plane;
  const u16* Kp  = qkv + (size_t)(B_*H_*S_*HD_) + plane;
  const u16* Vtp = qkv + 2*(size_t)(B_*H_*S_*HD_) + plane;   // [d][s]
  const float* maskS = maskScaled + (size_t)bI * S_ + g * 1024;

  const int t = threadIdx.x, lane = t & 63, wave = t >> 6;
  const int cl = lane & 31, hf = lane >> 5;
  const int x7 = cl & 7;
  const int hx16 = (hf ^ x7) << 4;                 // read-side chunk XOR (bytes)
  const int rg = (cl >> 3) * 1056 + x7 * 128;      // group-padded row base (row cl)

  __shared__ __align__(16) u16 Ks_[4224];          // 8 groups x 1056B, single buffer
  __shared__ __align__(16) u16 Vs_[4224];

  const int q0 = j * 128 + wave * 32;
  bf16x8 qf[4];   // Q pre-scaled by C1_ at GEMM epilogue
  #pragma unroll
  for (int d = 0; d < 4; ++d)
    qf[d] = *reinterpret_cast<const bf16x8*>(
        Qp + (size_t)(q0 + cl) * HD_ + d * 16 + hf * 8);

  // staging: pre-swizzled source (slot s of row r holds global chunk s^(r&7)), linear dest
  const int sr = t >> 3;                                     // row 0..31 within half
  const int scol = ((t & 7) ^ (sr & 7)) << 3;                // element col
  const u16* kSrc = Kp  + (size_t)(g * 1024 + sr) * HD_ + scol;
  const u16* vSrc = Vtp + (size_t)sr * S_ + g * 1024 + scol;
  const int dst0 = wave * 528, dst1 = (4 + wave) * 528;      // u16 offsets (1056B groups)

  f32x16 oacc0 = {}, oacc1 = {};
  float dm = 0.f, lsum = 0.f;

  GLOAD16(kSrc,                   &Ks_[dst0]);
  GLOAD16(kSrc + 32 * HD_,        &Ks_[dst1]);
  GLOAD16(vSrc,                   &Vs_[dst0]);
  GLOAD16(vSrc + 32 * (size_t)S_, &Vs_[dst1]);

  for (int kv0 = 0; kv0 < 1024; kv0 += 64) {
    __syncthreads();   // drains staging vmcnt: Ks_/Vs_ ready
    const char* Ks = (const char*)Ks_;
    const char* Vs = (const char*)Vs_;

    // ---- single-sub pipeline: reuse K/S/V/mask register slots across the 2 subs ----
    #pragma unroll
    for (int sub = 0; sub < 2; ++sub) {
      const int so = sub * 4224;          // K sub-block byte offset
      const int vo = sub * 64;            // V kv-chunk byte offset
      bf16x8 kf[4];
      #pragma unroll
      for (int d = 0; d < 4; ++d)
        kf[d] = *reinterpret_cast<const bf16x8*>(Ks + so + rg + ((d << 5) ^ hx16));
      f32x16 s = {};
      __builtin_amdgcn_s_setprio(1);
      #pragma unroll
      for (int d = 0; d < 4; ++d)
        s = __builtin_amdgcn_mfma_f32_32x32x16_bf16(kf[d], qf[d], s, 0, 0, 0);
      __builtin_amdgcn_s_setprio(0);
      // V fragments (hoisted: LDS latency hides under softmax VALU)
      bf16x8 vf[4];
      vf[0] = *reinterpret_cast<const bf16x8*>(Vs + rg + ((vo + 0) ^ hx16));
      vf[1] = *reinterpret_cast<const bf16x8*>(Vs + rg + 4224 + ((vo + 0) ^ hx16));
      vf[2] = *reinterpret_cast<const bf16x8*>(Vs + rg + ((vo + 32) ^ hx16));
      vf[3] = *reinterpret_cast<const bf16x8*>(Vs + rg + 4224 + ((vo + 32) ^ hx16));
      float4 mk[4];
      #pragma unroll
      for (int i = 0; i < 4; ++i)
        mk[i] = *reinterpret_cast<const float4*>(&maskS[kv0 + sub*32 + 8*i + 4*hf]);
      bf16x8 pA, pB;
      sm_pack(s, mk, dm, lsum, oacc0, oacc1, pA, pB);
      __builtin_amdgcn_s_setprio(1);
      oacc0 = __builtin_amdgcn_mfma_f32_32x32x16_bf16(vf[0], pA, oacc0, 0, 0, 0);
      oacc1 = __builtin_amdgcn_mfma_f32_32x32x16_bf16(vf[1], pA, oacc1, 0, 0, 0);
      oacc0 = __builtin_amdgcn_mfma_f32_32x32x16_bf16(vf[2], pB, oacc0, 0, 0, 0);
      oacc1 = __builtin_amdgcn_mfma_f32_32x32x16_bf16(vf[3], pB, oacc1, 0, 0, 0);
      __builtin_amdgcn_s_setprio(0);
    }

    __syncthreads();   // all waves done reading Ks_/Vs_
    if (kv0 + 64 < 1024) {
      const u16* kn = kSrc + (size_t)(kv0 + 64) * HD_;
      const u16* vn = vSrc + (kv0 + 64);
      GLOAD16(kn,                   &Ks_[dst0]);
      GLOAD16(kn + 32 * HD_,        &Ks_[dst1]);
      GLOAD16(vn,                   &Vs_[dst0]);
      GLOAD16(vn + 32 * (size_t)S_, &Vs_[dst1]);
    }
  }

  // ---- epilogue: write UNNORMALIZED partials ----
  lsum += __shfl_xor(lsum, 32);        // full row sum for this half
  const int row = pidx * S_ + q0 + cl;
  if (g == 0) {
    float* orow = out + ((size_t)bI * S_ + q0 + cl) * D_ + hI * HD_;
    #pragma unroll
    for (int jj = 0; jj < 4; ++jj) {
      float4 o0 = {oacc0[4*jj], oacc0[4*jj+1], oacc0[4*jj+2], oacc0[4*jj+3]};
      float4 o1 = {oacc1[4*jj], oacc1[4*jj+1], oacc1[4*jj+2], oacc1[4*jj+3]};
      *reinterpret_cast<float4*>(orow + 8*jj + 4*hf)      = o0;
      *reinterpret_cast<float4*>(orow + 32 + 8*jj + 4*hf) = o1;
    }
    if (hf == 0) { l0a[row] = lsum; dm0a[row] = dm; }
  } else {
    u16* prow = part1 + (size_t)row * HD_;
    #pragma unroll
    for (int jj = 0; jj < 4; ++jj) {
      ushort4 u0 = {f2bu(oacc0[4*jj]), f2bu(oacc0[4*jj+1]), f2bu(oacc0[4*jj+2]), f2bu(oacc0[4*jj+3])};
      ushort4 u1 = {f2bu(oacc1[4*jj]), f2bu(oacc1[4*jj+1]), f2bu(oacc1[4*jj+2]), f2bu(oacc1[4*jj+3])};
      *reinterpret_cast<ushort4*>(prow + 8*jj + 4*hf)      = u0;
      *reinterpret_cast<ushort4*>(prow + 32 + 8*jj + 4*hf) = u1;
    }
    if (hf == 0) { l1a[row] = lsum; dm1a[row] = dm; }
  }
}

// ------------- merge: out = (o0*f0 + o1*f1) / (l0*f0 + l1*f1) -------------
__global__ __launch_bounds__(256) void merge_kernel(float* __restrict__ out,
    const u16* __restrict__ part1, const float* __restrict__ l0a,
    const float* __restrict__ dm0a, const float* __restrict__ l1a,
    const float* __restrict__ dm1a) {
  const int e = blockIdx.x * 256 + threadIdx.x;   // 1,048,576 threads
  const int row = e >> 4;                          // pidx*2048 + q
  const int d4 = (e & 15) << 2;
  const int pidx = row >> 11, q = row & (S_ - 1);
  const int bI = pidx >> 4, hI = pidx & 15;
  const float dm0 = dm0a[row], dm1 = dm1a[row];
  const float dd = fmaxf(dm0, dm1);
  const float f0 = __builtin_amdgcn_exp2f(dm0 - dd);
  const float f1 = __builtin_amdgcn_exp2f(dm1 - dd);
  const float rinv = 1.0f / (l0a[row] * f0 + l1a[row] * f1);
  float* op = out + ((size_t)bI * S_ + q) * D_ + hI * HD_ + d4;
  float4 o0 = *reinterpret_cast<const float4*>(op);
  ushort4 u1 = *reinterpret_cast<const ushort4*>(part1 + (size_t)row * HD_ + d4);
  float4 r;
  r.x = (o0.x * f0 + bu2f(u1.x) * f1) * rinv;
  r.y = (o0.y * f0 + bu2f(u1.y) * f1) * rinv;
  r.z = (o0.z * f0 + bu2f(u1.z) * f1) * rinv;
  r.w = (o0.w * f0 + bu2f(u1.w) * f1) * rinv;
  *reinterpret_cast<float4*>(op) = r;
}

extern "C" void kernel_launch(void* const* d_in, const int* in_sizes, int n_in,
                              void* d_out, int out_size, void* d_ws, size_t ws_size,
                              hipStream_t stream) {
  const float* x     = (const float*)d_in[0];
  const float* mask  = (const float*)d_in[1];
  const float* gamma = (const float*)d_in[2];
  const float* beta  = (const float*)d_in[3];
  const float* Wq    = (const float*)d_in[4];
  const float* Wk    = (const float*)d_in[5];
  const float* Wv    = (const float*)d_in[6];
  float* out = (float*)d_out;

  char* ws = (char*)d_ws;
  u16* hbuf = (u16*)ws;                                        // 8 MiB; reused as part1
  char* wtb = ws + (size_t)M_*D_*2;                            // 6 MiB; reused for l/dm
  u16* wt   = (u16*)wtb;
  u16* qkv  = (u16*)(ws + (size_t)M_*D_*2 + 3ull*D_*D_*2);     // 24 MiB
  float* maskScaled = (float*)(ws + (size_t)M_*D_*2 + 3ull*D_*D_*2 + 3ull*B_*H_*S_*HD_*2); // 16 KiB

  u16* part1 = hbuf;                  // 8.39 MiB (dead after gemm)
  float* l0a  = (float*)wtb;          // 4 x 256 KiB in dead wt region
  float* dm0a = (float*)(wtb + (1u<<18));
  float* l1a  = (float*)(wtb + (2u<<18));
  float* dm1a = (float*)(wtb + (3u<<18));

  hipLaunchKernelGGL(mask_prep, dim3(4), dim3(256), 0, stream, mask, maskScaled);
  hipLaunchKernelGGL(ln_kernel, dim3(M_), dim3(256), 0, stream, x, gamma, beta, hbuf);
  hipLaunchKernelGGL(wt_kernel, dim3(32, 32, 3), dim3(32, 8), 0, stream, Wq, Wk, Wv, wt);
  hipLaunchKernelGGL(qkv_gemm, dim3(8, 32, 3), dim3(256), 0, stream, hbuf, wt, qkv);
  hipLaunchKernelGGL(attn_kernel, dim3(1024), dim3(256), 0, stream, qkv, maskScaled,
                     out, part1, l0a, dm0a, l1a, dm1a);
  hipLaunchKernelGGL(merge_kernel, dim3(4096), dim3(256), 0, stream, out, part1,
                     l0a, dm0a, l1a, dm1a);
}

// Round 11
// 112.514 us; speedup vs baseline: 1.5184x; 1.0011x over previous
//
#include <hip/hip_runtime.h>
#include <hip/hip_bf16.h>
#include <cstdint>

#define B_ 2
#define S_ 2048
#define D_ 1024
#define H_ 16
#define HD_ 64
#define M_ (B_*S_)   // 4096

#define LOG2E 1.4426950408889634f
#define C1_ (0.125f * LOG2E)   // 1/sqrt(64) * log2(e), folded into Q at GEMM epilogue

typedef unsigned short u16;
typedef __bf16 bf16x8 __attribute__((ext_vector_type(8)));
typedef u16 u16x8 __attribute__((ext_vector_type(8)));
typedef float f32x4 __attribute__((ext_vector_type(4)));
typedef float f32x16 __attribute__((ext_vector_type(16)));
typedef int i32x4 __attribute__((ext_vector_type(4)));

static __device__ __forceinline__ u16 f2bu(float f) {
  __bf16 b = (__bf16)f;
  return __builtin_bit_cast(unsigned short, b);
}
static __device__ __forceinline__ float bu2f(u16 u) {
  unsigned int v = ((unsigned int)u) << 16;
  return __builtin_bit_cast(float, v);
}

static __device__ __forceinline__ int cvtpk(float a, float b) {
  int r;
  asm("v_cvt_pk_bf16_f32 %0, %1, %2" : "=v"(r) : "v"(a), "v"(b));
  return r;
}
static __device__ __forceinline__ void plswap(int &x, int &y) {
  asm("v_permlane32_swap_b32 %0, %1" : "+v"(x), "+v"(y));
}

#define GLOAD16(g, l) __builtin_amdgcn_global_load_lds( \
    (__attribute__((address_space(1))) void*)(g), \
    (__attribute__((address_space(3))) void*)(l), 16, 0, 0)

// ---------------- mask prep: maskScaled = mask*log2e - 8 ----------------
__global__ __launch_bounds__(256) void mask_prep(const float* __restrict__ mask,
    float* __restrict__ ms) {
  const int i = blockIdx.x * 256 + threadIdx.x;   // 1024 float4s
  float4 mv = reinterpret_cast<const float4*>(mask)[i];
  float4 sm = {mv.x * LOG2E - 8.0f, mv.y * LOG2E - 8.0f,
               mv.z * LOG2E - 8.0f, mv.w * LOG2E - 8.0f};
  reinterpret_cast<float4*>(ms)[i] = sm;
}

// ---------------- LayerNorm: fp32 [4096][1024] -> bf16 h ----------------
__global__ __launch_bounds__(256) void ln_kernel(const float* __restrict__ x,
    const float* __restrict__ g, const float* __restrict__ be, u16* __restrict__ h) {
  const int row = blockIdx.x;
  const int t = threadIdx.x;
  float4 v = reinterpret_cast<const float4*>(x + (size_t)row * D_)[t];
  float s = v.x + v.y + v.z + v.w;
  float sq = v.x*v.x + v.y*v.y + v.z*v.z + v.w*v.w;
  #pragma unroll
  for (int off = 32; off >= 1; off >>= 1) {
    s  += __shfl_down(s, off);
    sq += __shfl_down(sq, off);
  }
  __shared__ float red[8];
  const int wave = t >> 6, lane = t & 63;
  if (lane == 0) { red[wave] = s; red[4 + wave] = sq; }
  __syncthreads();
  if (t == 0) {
    float ts = red[0]+red[1]+red[2]+red[3];
    float tq = red[4]+red[5]+red[6]+red[7];
    float mu = ts * (1.0f / D_);
    red[0] = mu;
    red[1] = rsqrtf(tq * (1.0f / D_) - mu*mu + 1e-5f);
  }
  __syncthreads();
  const float mu = red[0], rs = red[1];
  float4 gg = reinterpret_cast<const float4*>(g)[t];
  float4 bb = reinterpret_cast<const float4*>(be)[t];
  ushort4 o;
  o.x = f2bu((v.x - mu) * rs * gg.x + bb.x);
  o.y = f2bu((v.y - mu) * rs * gg.y + bb.y);
  o.z = f2bu((v.z - mu) * rs * gg.z + bb.z);
  o.w = f2bu((v.w - mu) * rs * gg.w + bb.w);
  reinterpret_cast<ushort4*>(h + (size_t)row * D_)[t] = o;
}

// ------------- Weight transpose+convert: W[k][n] fp32 -> Wt[n][k] bf16 -------------
__global__ __launch_bounds__(256) void wt_kernel(const float* __restrict__ W0,
    const float* __restrict__ W1, const float* __restrict__ W2, u16* __restrict__ wt) {
  const int z = blockIdx.z;
  const float* W = (z == 0) ? W0 : ((z == 1) ? W1 : W2);
  u16* out = wt + (size_t)z * D_ * D_;
  __shared__ float tile[32][33];
  const int n0 = blockIdx.x * 32, k0 = blockIdx.y * 32;
  const int tx = threadIdx.x, ty = threadIdx.y;
  #pragma unroll
  for (int j = 0; j < 4; ++j)
    tile[ty + 8*j][tx] = W[(size_t)(k0 + ty + 8*j) * D_ + n0 + tx];
  __syncthreads();
  #pragma unroll
  for (int j = 0; j < 4; ++j)
    out[(size_t)(n0 + ty + 8*j) * D_ + k0 + tx] = f2bu(tile[tx][ty + 8*j]);
}

// ------------- QKV GEMM: 128x128 tile, BK=32, T2-swizzled LDS -------------
// Q scaled by C1_ and stored [B,H,S,HD]; K [B,H,S,HD]; V TRANSPOSED [B,H,HD,S].
__global__ __launch_bounds__(256) void qkv_gemm(const u16* __restrict__ hbuf,
    const u16* __restrict__ wt, u16* __restrict__ qkv) {
  const int z = blockIdx.z;
  const u16* Bt = wt + (size_t)z * D_ * D_;
  u16* outp = qkv + (size_t)z * (B_*H_*S_*HD_);
  __shared__ __align__(16) u16 As[128 * 32];
  __shared__ __align__(16) u16 Bs[128 * 32];
  const int t = threadIdx.x, lane = t & 63, wave = t >> 6;
  const int row0 = blockIdx.y * 128, col0 = blockIdx.x * 128;
  const int wm = wave >> 1, wn = wave & 1;
  f32x4 acc[4][4] = {};
  const int schunk = (t & 3) ^ ((t >> 3) & 3);
  const u16* ag = hbuf + (size_t)(row0 + (t >> 2)) * D_ + schunk * 8;
  const u16* bg = Bt   + (size_t)(col0 + (t >> 2)) * D_ + schunk * 8;
  u16* lA = &As[wave * 512];
  u16* lB = &Bs[wave * 512];
  const char* Ac = (const char*)As;
  const char* Bc = (const char*)Bs;
  const int cbase = (((lane >> 4) ^ ((lane >> 1) & 3)) << 4);

  for (int k0 = 0; k0 < D_; k0 += 32) {
    GLOAD16(ag + k0,           lA);
    GLOAD16(ag + k0 + 64 * D_, lA + 2048);
    GLOAD16(bg + k0,           lB);
    GLOAD16(bg + k0 + 64 * D_, lB + 2048);
    __syncthreads();
    bf16x8 af[4], bfr[4];
    #pragma unroll
    for (int m = 0; m < 4; ++m)
      af[m] = *reinterpret_cast<const bf16x8*>(Ac + (wm*64 + m*16 + (lane & 15)) * 64 + cbase);
    #pragma unroll
    for (int n = 0; n < 4; ++n)
      bfr[n] = *reinterpret_cast<const bf16x8*>(Bc + (wn*64 + n*16 + (lane & 15)) * 64 + cbase);
    #pragma unroll
    for (int m = 0; m < 4; ++m) {
      #pragma unroll
      for (int n = 0; n < 4; ++n)
        acc[m][n] = __builtin_amdgcn_mfma_f32_16x16x32_bf16(af[m], bfr[n], acc[m][n], 0, 0, 0);
    }
    __syncthreads();
  }
  const float scl = (z == 0) ? C1_ : 1.0f;   // fold 1/sqrt(d)*log2e into Q
  #pragma unroll
  for (int m = 0; m < 4; ++m) {
    #pragma unroll
    for (int n = 0; n < 4; ++n) {
      const int gcol = col0 + wn*64 + n*16 + (lane & 15);
      const int hI = gcol >> 6, dI = gcol & 63;
      const int grow0 = row0 + wm*64 + m*16 + (lane >> 4) * 4;
      const int bI = grow0 >> 11, sI0 = grow0 & (S_ - 1);
      if (z == 2) {
        // V^T: lane holds 4 CONSECUTIVE s for one d -> one 8B store
        ushort4 u = {f2bu(acc[m][n][0]), f2bu(acc[m][n][1]),
                     f2bu(acc[m][n][2]), f2bu(acc[m][n][3])};
        *reinterpret_cast<ushort4*>(
            outp + ((size_t)(bI * H_ + hI) * HD_ + dI) * S_ + sI0) = u;
      } else {
        #pragma unroll
        for (int r = 0; r < 4; ++r)
          outp[((size_t)(bI * H_ + hI) * S_ + sI0 + r) * HD_ + dI] =
              f2bu(acc[m][n][r] * scl);
      }
    }
  }
}

// ---- softmax + pack; defer-max, NO hot-path cross-lane ops (validated r4/r5) ----
static __device__ __forceinline__ void sm_pack(
    const f32x16& s, const float4* __restrict__ mk,
    float& dm, float& lsum, f32x16& o0, f32x16& o1,
    bf16x8& pfA, bf16x8& pfB) {
  float zb[16];
  #pragma unroll
  for (int r = 0; r < 4; ++r) {
    zb[r]      = s[r]      + ((const float*)&mk[0])[r];
    zb[r + 4]  = s[r + 4]  + ((const float*)&mk[1])[r];
    zb[r + 8]  = s[r + 8]  + ((const float*)&mk[2])[r];
    zb[r + 12] = s[r + 12] + ((const float*)&mk[3])[r];
  }
  float a0 = fmaxf(fmaxf(zb[0], zb[1]), zb[2]);
  float a1 = fmaxf(fmaxf(zb[3], zb[4]), zb[5]);
  float a2 = fmaxf(fmaxf(zb[6], zb[7]), zb[8]);
  float a3 = fmaxf(fmaxf(zb[9], zb[10]), zb[11]);
  float a4 = fmaxf(fmaxf(zb[12], zb[13]), zb[14]);
  float tm = fmaxf(fmaxf(fmaxf(a0, a1), fmaxf(a2, a3)), fmaxf(a4, zb[15]));
  if (__builtin_expect(__any(tm > dm + 8.0f), 0)) {   // cold rescale
    float tp = fmaxf(tm, __shfl_xor(tm, 32));         // full row max (q = cl)
    float dnew = fmaxf(dm, tp - 8.0f);
    float sf = __builtin_amdgcn_exp2f(dm - dnew);
    lsum *= sf; o0 = o0 * sf; o1 = o1 * sf; dm = dnew;
  }
  float p[16];
  #pragma unroll
  for (int r = 0; r < 16; ++r) p[r] = __builtin_amdgcn_exp2f(zb[r] - dm);
  float s01 = (p[0] + p[1]) + (p[2] + p[3]);
  float s23 = (p[4] + p[5]) + (p[6] + p[7]);
  float s45 = (p[8] + p[9]) + (p[10] + p[11]);
  float s67 = (p[12] + p[13]) + (p[14] + p[15]);
  lsum += (s01 + s23) + (s45 + s67);   // cross-half combine deferred to epilogue
  int pk01 = cvtpk(p[0], p[1]),   pk23 = cvtpk(p[2], p[3]);
  int pk45 = cvtpk(p[4], p[5]),   pk67 = cvtpk(p[6], p[7]);
  int pk89 = cvtpk(p[8], p[9]),   pkAB = cvtpk(p[10], p[11]);
  int pkCD = cvtpk(p[12], p[13]), pkEF = cvtpk(p[14], p[15]);
  plswap(pk01, pk45); plswap(pk23, pk67);
  plswap(pk89, pkCD); plswap(pkAB, pkEF);
  i32x4 c0 = {pk01, pk23, pk45, pk67};
  i32x4 c1 = {pk89, pkAB, pkCD, pkEF};
  pfA = __builtin_bit_cast(bf16x8, c0);
  pfB = __builtin_bit_cast(bf16x8, c1);
}

// ------------- Flash attention: kv-split across blocks, SINGLE-buffered K/V -------------
// Grid 1024 = 8 XCD x (16 qtile x 2 kvhalf) x 4 plane-groups.
// LDS layout: r2-style LINEAR [64 rows][128B] (NO group padding) — measured 4
// conflict-cycles/b128 vs 8 for the 1056B group-padded variant (r5-r10).
__global__ __launch_bounds__(256, 3) void attn_kernel(const u16* __restrict__ qkv,
    const float* __restrict__ maskScaled, float* __restrict__ out,
    u16* __restrict__ part1, float* __restrict__ l0a, float* __restrict__ dm0a,
    float* __restrict__ l1a, float* __restrict__ dm1a) {
  const int bid = blockIdx.x;
  const int x = bid & 7, rr = bid >> 3;
  const int w = rr & 31;                    // 16 qtiles x 2 halves per plane
  const int pidx = x + ((rr >> 5) << 3);    // plane 0..31 = b*16+h
  const int j = w & 15, g = w >> 4;
  const int hI = pidx & 15, bI = pidx >> 4;
  const size_t plane = (size_t)pidx * (S_ * HD_);
  const u16* Qp  = qkv + plane;
  const u16* Kp  = qkv + (size_t)(B_*H_*S_*HD_) + plane;
  const u16* Vtp = qkv + 2*(size_t)(B_*H_*S_*HD_) + plane;   // [d][s]
  const float* maskS = maskScaled + (size_t)bI * S_ + g * 1024;

  const int t = threadIdx.x, lane = t & 63, wave = t >> 6;
  const int cl = lane & 31, hf = lane >> 5;
  const int x7 = cl & 7;
  const int hx16 = (hf ^ x7) << 4;                 // read-side chunk XOR (bytes)
  const int rg = cl * 128;                         // linear row base (row cl), bytes

  __shared__ __align__(16) u16 Ks_[4096];          // [64][64] u16 = 8KB, single buffer
  __shared__ __align__(16) u16 Vs_[4096];

  const int q0 = j * 128 + wave * 32;
  bf16x8 qf[4];   // Q pre-scaled by C1_ at GEMM epilogue
  #pragma unroll
  for (int d = 0; d < 4; ++d)
    qf[d] = *reinterpret_cast<const bf16x8*>(
        Qp + (size_t)(q0 + cl) * HD_ + d * 16 + hf * 8);

  // staging: pre-swizzled source (slot s of row r holds global chunk s^(r&7)), linear dest
  const int sr = t >> 3;                                     // row 0..31 within half
  const int scol = ((t & 7) ^ (sr & 7)) << 3;                // element col
  const u16* kSrc = Kp  + (size_t)(g * 1024 + sr) * HD_ + scol;
  const u16* vSrc = Vtp + (size_t)sr * S_ + g * 1024 + scol;
  const int dst0 = wave * 512, dst1 = 2048 + wave * 512;     // u16 offsets (1024B/wave)

  f32x16 oacc0 = {}, oacc1 = {};
  float dm = 0.f, lsum = 0.f;

  GLOAD16(kSrc,                   &Ks_[dst0]);
  GLOAD16(kSrc + 32 * HD_,        &Ks_[dst1]);
  GLOAD16(vSrc,                   &Vs_[dst0]);
  GLOAD16(vSrc + 32 * (size_t)S_, &Vs_[dst1]);

  for (int kv0 = 0; kv0 < 1024; kv0 += 64) {
    __syncthreads();   // drains staging vmcnt: Ks_/Vs_ ready
    const char* Ks = (const char*)Ks_;
    const char* Vs = (const char*)Vs_;

    // ---- single-sub pipeline: reuse K/S/V/mask register slots across the 2 subs ----
    #pragma unroll
    for (int sub = 0; sub < 2; ++sub) {
      const int so = sub * 4096;          // K sub-block byte offset (rows 32..63)
      const int vo = sub * 64;            // V kv-chunk byte offset
      bf16x8 kf[4];
      #pragma unroll
      for (int d = 0; d < 4; ++d)
        kf[d] = *reinterpret_cast<const bf16x8*>(Ks + so + rg + ((d << 5) ^ hx16));
      f32x16 s = {};
      __builtin_amdgcn_s_setprio(1);
      #pragma unroll
      for (int d = 0; d < 4; ++d)
        s = __builtin_amdgcn_mfma_f32_32x32x16_bf16(kf[d], qf[d], s, 0, 0, 0);
      __builtin_amdgcn_s_setprio(0);
      // V fragments (hoisted: LDS latency hides under softmax VALU)
      bf16x8 vf[4];
      vf[0] = *reinterpret_cast<const bf16x8*>(Vs + rg + ((vo + 0) ^ hx16));
      vf[1] = *reinterpret_cast<const bf16x8*>(Vs + rg + 4096 + ((vo + 0) ^ hx16));
      vf[2] = *reinterpret_cast<const bf16x8*>(Vs + rg + ((vo + 32) ^ hx16));
      vf[3] = *reinterpret_cast<const bf16x8*>(Vs + rg + 4096 + ((vo + 32) ^ hx16));
      float4 mk[4];
      #pragma unroll
      for (int i = 0; i < 4; ++i)
        mk[i] = *reinterpret_cast<const float4*>(&maskS[kv0 + sub*32 + 8*i + 4*hf]);
      bf16x8 pA, pB;
      sm_pack(s, mk, dm, lsum, oacc0, oacc1, pA, pB);
      __builtin_amdgcn_s_setprio(1);
      oacc0 = __builtin_amdgcn_mfma_f32_32x32x16_bf16(vf[0], pA, oacc0, 0, 0, 0);
      oacc1 = __builtin_amdgcn_mfma_f32_32x32x16_bf16(vf[1], pA, oacc1, 0, 0, 0);
      oacc0 = __builtin_amdgcn_mfma_f32_32x32x16_bf16(vf[2], pB, oacc0, 0, 0, 0);
      oacc1 = __builtin_amdgcn_mfma_f32_32x32x16_bf16(vf[3], pB, oacc1, 0, 0, 0);
      __builtin_amdgcn_s_setprio(0);
    }

    __syncthreads();   // all waves done reading Ks_/Vs_
    if (kv0 + 64 < 1024) {
      const u16* kn = kSrc + (size_t)(kv0 + 64) * HD_;
      const u16* vn = vSrc + (kv0 + 64);
      GLOAD16(kn,                   &Ks_[dst0]);
      GLOAD16(kn + 32 * HD_,        &Ks_[dst1]);
      GLOAD16(vn,                   &Vs_[dst0]);
      GLOAD16(vn + 32 * (size_t)S_, &Vs_[dst1]);
    }
  }

  // ---- epilogue: write UNNORMALIZED partials ----
  lsum += __shfl_xor(lsum, 32);        // full row sum for this half
  const int row = pidx * S_ + q0 + cl;
  if (g == 0) {
    float* orow = out + ((size_t)bI * S_ + q0 + cl) * D_ + hI * HD_;
    #pragma unroll
    for (int jj = 0; jj < 4; ++jj) {
      float4 o0 = {oacc0[4*jj], oacc0[4*jj+1], oacc0[4*jj+2], oacc0[4*jj+3]};
      float4 o1 = {oacc1[4*jj], oacc1[4*jj+1], oacc1[4*jj+2], oacc1[4*jj+3]};
      *reinterpret_cast<float4*>(orow + 8*jj + 4*hf)      = o0;
      *reinterpret_cast<float4*>(orow + 32 + 8*jj + 4*hf) = o1;
    }
    if (hf == 0) { l0a[row] = lsum; dm0a[row] = dm; }
  } else {
    u16* prow = part1 + (size_t)row * HD_;
    #pragma unroll
    for (int jj = 0; jj < 4; ++jj) {
      ushort4 u0 = {f2bu(oacc0[4*jj]), f2bu(oacc0[4*jj+1]), f2bu(oacc0[4*jj+2]), f2bu(oacc0[4*jj+3])};
      ushort4 u1 = {f2bu(oacc1[4*jj]), f2bu(oacc1[4*jj+1]), f2bu(oacc1[4*jj+2]), f2bu(oacc1[4*jj+3])};
      *reinterpret_cast<ushort4*>(prow + 8*jj + 4*hf)      = u0;
      *reinterpret_cast<ushort4*>(prow + 32 + 8*jj + 4*hf) = u1;
    }
    if (hf == 0) { l1a[row] = lsum; dm1a[row] = dm; }
  }
}

// ------------- merge: out = (o0*f0 + o1*f1) / (l0*f0 + l1*f1) -------------
__global__ __launch_bounds__(256) void merge_kernel(float* __restrict__ out,
    const u16* __restrict__ part1, const float* __restrict__ l0a,
    const float* __restrict__ dm0a, const float* __restrict__ l1a,
    const float* __restrict__ dm1a) {
  const int e = blockIdx.x * 256 + threadIdx.x;   // 1,048,576 threads
  const int row = e >> 4;                          // pidx*2048 + q
  const int d4 = (e & 15) << 2;
  const int pidx = row >> 11, q = row & (S_ - 1);
  const int bI = pidx >> 4, hI = pidx & 15;
  const float dm0 = dm0a[row], dm1 = dm1a[row];
  const float dd = fmaxf(dm0, dm1);
  const float f0 = __builtin_amdgcn_exp2f(dm0 - dd);
  const float f1 = __builtin_amdgcn_exp2f(dm1 - dd);
  const float rinv = 1.0f / (l0a[row] * f0 + l1a[row] * f1);
  float* op = out + ((size_t)bI * S_ + q) * D_ + hI * HD_ + d4;
  float4 o0 = *reinterpret_cast<const float4*>(op);
  ushort4 u1 = *reinterpret_cast<const ushort4*>(part1 + (size_t)row * HD_ + d4);
  float4 r;
  r.x = (o0.x * f0 + bu2f(u1.x) * f1) * rinv;
  r.y = (o0.y * f0 + bu2f(u1.y) * f1) * rinv;
  r.z = (o0.z * f0 + bu2f(u1.z) * f1) * rinv;
  r.w = (o0.w * f0 + bu2f(u1.w) * f1) * rinv;
  *reinterpret_cast<float4*>(op) = r;
}

extern "C" void kernel_launch(void* const* d_in, const int* in_sizes, int n_in,
                              void* d_out, int out_size, void* d_ws, size_t ws_size,
                              hipStream_t stream) {
  const float* x     = (const float*)d_in[0];
  const float* mask  = (const float*)d_in[1];
  const float* gamma = (const float*)d_in[2];
  const float* beta  = (const float*)d_in[3];
  const float* Wq    = (const float*)d_in[4];
  const float* Wk    = (const float*)d_in[5];
  const float* Wv    = (const float*)d_in[6];
  float* out = (float*)d_out;

  char* ws = (char*)d_ws;
  u16* hbuf = (u16*)ws;                                        // 8 MiB; reused as part1
  char* wtb = ws + (size_t)M_*D_*2;                            // 6 MiB; reused for l/dm
  u16* wt   = (u16*)wtb;
  u16* qkv  = (u16*)(ws + (size_t)M_*D_*2 + 3ull*D_*D_*2);     // 24 MiB
  float* maskScaled = (float*)(ws + (size_t)M_*D_*2 + 3ull*D_*D_*2 + 3ull*B_*H_*S_*HD_*2); // 16 KiB

  u16* part1 = hbuf;                  // 8.39 MiB (dead after gemm)
  float* l0a  = (float*)wtb;          // 4 x 256 KiB in dead wt region
  float* dm0a = (float*)(wtb + (1u<<18));
  float* l1a  = (float*)(wtb + (2u<<18));
  float* dm1a = (float*)(wtb + (3u<<18));

  hipLaunchKernelGGL(mask_prep, dim3(4), dim3(256), 0, stream, mask, maskScaled);
  hipLaunchKernelGGL(ln_kernel, dim3(M_), dim3(256), 0, stream, x, gamma, beta, hbuf);
  hipLaunchKernelGGL(wt_kernel, dim3(32, 32, 3), dim3(32, 8), 0, stream, Wq, Wk, Wv, wt);
  hipLaunchKernelGGL(qkv_gemm, dim3(8, 32, 3), dim3(256), 0, stream, hbuf, wt, qkv);
  hipLaunchKernelGGL(attn_kernel, dim3(1024), dim3(256), 0, stream, qkv, maskScaled,
                     out, part1, l0a, dm0a, l1a, dm1a);
  hipLaunchKernelGGL(merge_kernel, dim3(4096), dim3(256), 0, stream, out, part1,
                     l0a, dm0a, l1a, dm1a);
}